// Round 4
// baseline (516.947 us; speedup 1.0000x reference)
//
#include <hip/hip_runtime.h>
#include <hip/hip_bf16.h>
#include <cstdint>

#define NLOC 128        // nodes per graph
#define NGRAPH 128      // bs*T
#define NNODE 16384     // total nodes
#define EBASE 2048      // base edges per graph
#define CSTRIDE 256     // csr col stride per local node

typedef _Float16 half2v __attribute__((ext_vector_type(2)));

__device__ __forceinline__ float sigf(float x) { return 1.f / (1.f + __expf(-x)); }
__device__ __forceinline__ float tanhfast(float x) {
    float e = __expf(2.f * x);
    return 1.f - 2.f / (e + 1.f);
}
__device__ __forceinline__ uint32_t packh2(float a, float b) {
    half2v v;
    v.x = (_Float16)a; v.y = (_Float16)b;
    return __builtin_bit_cast(uint32_t, v);
}
__device__ __forceinline__ float dot2(uint32_t w, uint32_t h, float acc) {
#if __has_builtin(__builtin_amdgcn_fdot2)
    return __builtin_amdgcn_fdot2(__builtin_bit_cast(half2v, w),
                                  __builtin_bit_cast(half2v, h), acc, false);
#else
    half2v wv = __builtin_bit_cast(half2v, w);
    half2v hv = __builtin_bit_cast(half2v, h);
    return acc + (float)wv.x * (float)hv.x + (float)wv.y * (float)hv.y;
#endif
}

// ---------------- CSR of the shared per-graph edge list (dst -> list of src) ----------------
__global__ __launch_bounds__(1024) void build_csr_kernel(const int* __restrict__ ei,
                                                         int* __restrict__ cnt,
                                                         int* __restrict__ col) {
    __shared__ int c8[NLOC][8];
    int tid = threadIdx.x;
    int v = tid >> 3, p = tid & 7;
    const int* srcs = ei;
    const int* dsts = ei + EBASE;
    int e0 = p * 256, e1 = e0 + 256;
    int c = 0;
    for (int e = e0; e < e1; ++e) c += (dsts[e] == v);
    c8[v][p] = c;
    __syncthreads();
    int start = 0;
    for (int q = 0; q < p; ++q) start += c8[v][q];
    if (p == 0) {
        int tot = 0;
        for (int q = 0; q < 8; ++q) tot += c8[v][q];
        cnt[v] = tot;
    }
    int w = start;
    for (int e = e0; e < e1; ++e)
        if (dsts[e] == v) col[v * CSTRIDE + (w++)] = srcs[e];
}

// ---------------- fp32 tiled GEMM: C[M,N] = A[M,K] @ B[K,N]; M%64==0, N%64==0, K%16==0 ----
__global__ __launch_bounds__(256) void gemm_kernel(const float* __restrict__ A,
                                                   const float* __restrict__ B,
                                                   float* __restrict__ C,
                                                   int M, int N, int K) {
    __shared__ __align__(16) float As[16][64];
    __shared__ __align__(16) float Bs[16][64];
    int tid = threadIdx.x;
    int bm = blockIdx.y, bn = blockIdx.x;
    int am = tid >> 2, ak = (tid & 3) << 2;
    int bk = tid >> 4, bn4 = (tid & 15) << 2;
    int ty = tid >> 4, tx = tid & 15;
    const float* Ab = A + (size_t)bm * 64 * K;
    const float* Bb = B + bn * 64;
    float acc[4][4] = {};
    for (int k0 = 0; k0 < K; k0 += 16) {
        float4 av = *(const float4*)(Ab + (size_t)am * K + k0 + ak);
        float4 bv = *(const float4*)(Bb + (size_t)(k0 + bk) * N + bn4);
        As[ak + 0][am] = av.x; As[ak + 1][am] = av.y;
        As[ak + 2][am] = av.z; As[ak + 3][am] = av.w;
        *(float4*)&Bs[bk][bn4] = bv;
        __syncthreads();
#pragma unroll
        for (int kk = 0; kk < 16; ++kk) {
            float4 a4 = *(const float4*)&As[kk][ty << 2];
            float4 b4 = *(const float4*)&Bs[kk][tx << 2];
            acc[0][0] += a4.x * b4.x; acc[0][1] += a4.x * b4.y; acc[0][2] += a4.x * b4.z; acc[0][3] += a4.x * b4.w;
            acc[1][0] += a4.y * b4.x; acc[1][1] += a4.y * b4.y; acc[1][2] += a4.y * b4.z; acc[1][3] += a4.y * b4.w;
            acc[2][0] += a4.z * b4.x; acc[2][1] += a4.z * b4.y; acc[2][2] += a4.z * b4.z; acc[2][3] += a4.z * b4.w;
            acc[3][0] += a4.w * b4.x; acc[3][1] += a4.w * b4.y; acc[3][2] += a4.w * b4.z; acc[3][3] += a4.w * b4.w;
        }
        __syncthreads();
    }
    float* Cb = C + (size_t)(bm * 64 + ty * 4) * N + bn * 64 + tx * 4;
#pragma unroll
    for (int i = 0; i < 4; ++i)
        *(float4*)(Cb + (size_t)i * N) = make_float4(acc[i][0], acc[i][1], acc[i][2], acc[i][3]);
}

// ---------------- attention dot products per node ----------------
template <int H>
__global__ __launch_bounds__(256) void att_kernel(const float* __restrict__ hf,
                                                  const float* __restrict__ a_s,
                                                  const float* __restrict__ a_d,
                                                  float* __restrict__ asb,
                                                  float* __restrict__ adb) {
    int lane = threadIdx.x & 63;
    int n = blockIdx.x * 4 + (threadIdx.x >> 6);
    const float* row = hf + (size_t)n * (H * 64);
#pragma unroll
    for (int h = 0; h < H; ++h) {
        float v = row[h * 64 + lane];
        float ps = v * a_s[h * 64 + lane];
        float pd = v * a_d[h * 64 + lane];
#pragma unroll
        for (int off = 32; off > 0; off >>= 1) {
            ps += __shfl_xor(ps, off, 64);
            pd += __shfl_xor(pd, off, 64);
        }
        if (lane == 0) { asb[n * H + h] = ps; adb[n * H + h] = pd; }
    }
}

// ---------------- GAT aggregation: softmax over in-edges, gather, +bias, ReLU -------------
template <int H>
__global__ __launch_bounds__(256) void agg_kernel(const float* __restrict__ hf,
                                                  const float* __restrict__ asb,
                                                  const float* __restrict__ adb,
                                                  const int* __restrict__ cnt,
                                                  const int* __restrict__ col,
                                                  const float* __restrict__ bias,
                                                  float* __restrict__ out) {
    __shared__ float e_lds[4][96][H];
    __shared__ int u_lds[4][96];
    int lane = threadIdx.x & 63, w = threadIdx.x >> 6;
    int n = blockIdx.x * 4 + w;
    int v = n & 127, base = n & ~127;
    int deg = cnt[v];
    int tot = min(deg + 1, 96);
    float adst[H];
#pragma unroll
    for (int h = 0; h < H; ++h) adst[h] = adb[n * H + h];
    for (int k = lane; k < tot; k += 64) {
        int u = (k < deg) ? col[v * CSTRIDE + k] : v;
        u_lds[w][k] = u;
#pragma unroll
        for (int h = 0; h < H; ++h) {
            float e = asb[(base + u) * H + h] + adst[h];
            e_lds[w][k][h] = (e > 0.f) ? e : 0.2f * e;
        }
    }
    __syncthreads();
    float m[H];
#pragma unroll
    for (int h = 0; h < H; ++h) m[h] = -1e30f;
    for (int k = 0; k < tot; ++k)
#pragma unroll
        for (int h = 0; h < H; ++h) m[h] = fmaxf(m[h], e_lds[w][k][h]);
    __syncthreads();
    for (int k = lane; k < tot; k += 64)
#pragma unroll
        for (int h = 0; h < H; ++h) e_lds[w][k][h] = __expf(e_lds[w][k][h] - m[h]);
    __syncthreads();
    float den[H], acc[H];
#pragma unroll
    for (int h = 0; h < H; ++h) { den[h] = 0.f; acc[h] = 0.f; }
    for (int k = 0; k < tot; ++k) {
        int u = u_lds[w][k];
        const float* hr = hf + (size_t)(base + u) * (H * 64);
#pragma unroll
        for (int h = 0; h < H; ++h) {
            float wgt = e_lds[w][k][h];
            den[h] += wgt;
            acc[h] += wgt * hr[h * 64 + lane];
        }
    }
#pragma unroll
    for (int h = 0; h < H; ++h) {
        float o = acc[h] / (den[h] + 1e-16f) + bias[h * 64 + lane];
        out[(size_t)n * (H * 64) + h * 64 + lane] = fmaxf(o, 0.f);
    }
}

// ---------------- graph sum-pool into sequence layout [t*4+b][64] ----------------
__global__ void pool_kernel(const float* __restrict__ h, float* __restrict__ gemb) {
    int g = blockIdx.x;       // g = b*32 + t
    int c = threadIdx.x;      // 64 threads
    int b = g >> 5, t = g & 31;
    float s = 0.f;
    const float* p = h + (size_t)g * 128 * 64 + c;
    for (int vv = 0; vv < 128; ++vv) s += p[vv * 64];
    gemb[(t * 4 + b) * 64 + c] = s;
}

// ---------------- LSTM input part: xp[dir][r][o] = seq[r] . Wih[o] + bih[o] + bhh[o] ------
__global__ __launch_bounds__(256) void xpart_kernel(const float* __restrict__ gemb,
                                                    const float* __restrict__ Wf, const float* __restrict__ bif, const float* __restrict__ bhf,
                                                    const float* __restrict__ Wb, const float* __restrict__ bib, const float* __restrict__ bhb,
                                                    float* __restrict__ xp) {
    __shared__ float a[64];
    int r = blockIdx.x, tid = threadIdx.x;
    if (tid < 64) a[tid] = gemb[r * 64 + tid];
    __syncthreads();
    for (int dir = 0; dir < 2; ++dir) {
        const float* W = dir ? Wb : Wf;
        const float* bi = dir ? bib : bif;
        const float* bh = dir ? bhb : bhf;
        for (int o = tid; o < 1024; o += 256) {
            const float* wr = W + (size_t)o * 64;
            float s = bi[o] + bh[o];
#pragma unroll
            for (int k = 0; k < 64; k += 4) {
                float4 wv = *(const float4*)(wr + k);
                s += a[k] * wv.x + a[k + 1] * wv.y + a[k + 2] * wv.z + a[k + 3] * wv.w;
            }
            xp[dir * 131072 + r * 1024 + o] = s;
        }
    }
}

// ---------------- pre-pack Whh to f16 pairs: reg part [dir][chunk i][row] (uint4),
//                  tail part transposed [dir][ku][row] (u32) ----------------
__global__ __launch_bounds__(256) void wpack_kernel(const float* __restrict__ Whh_f,
                                                    const float* __restrict__ Whh_b,
                                                    uint32_t* __restrict__ wreg,
                                                    uint32_t* __restrict__ wtail) {
    int gid = blockIdx.x * 256 + threadIdx.x;   // 0..2047
    int dir = gid >> 10, row = gid & 1023;
    const float* src = (dir ? Whh_b : Whh_f) + (size_t)row * 256;
    // cols 0..191 -> 24 uint4 chunks (8 cols each), coalesced-by-row layout
    uint4* wr4 = (uint4*)wreg;
#pragma unroll
    for (int i = 0; i < 24; ++i) {
        uint4 v;
        v.x = packh2(src[i * 8 + 0], src[i * 8 + 1]);
        v.y = packh2(src[i * 8 + 2], src[i * 8 + 3]);
        v.z = packh2(src[i * 8 + 4], src[i * 8 + 5]);
        v.w = packh2(src[i * 8 + 6], src[i * 8 + 7]);
        wr4[(size_t)(dir * 24 + i) * 1024 + row] = v;
    }
    // cols 192..255 -> 32 u32, transposed [ku][row]
#pragma unroll
    for (int ku = 0; ku < 32; ++ku) {
        wtail[(size_t)(dir * 32 + ku) * 1024 + row] =
            packh2(src[192 + ku * 2], src[192 + ku * 2 + 1]);
    }
}

// ---------------- BiLSTM recurrent: 8 blocks (dir x batch), 256 threads ------------------
// Thread t owns ALL 4 gate rows of cell t (rows t, 256+t, 512+t, 768+t): the c/h update is
// thread-local (no gv roundtrip). Weights: cols 0..191 in 4x96 VGPRs (f16 pairs, dot2),
// cols 192..255 in LDS [ku][row] (conflict-free b32). 256 thr + min-1 bound -> 512-VGPR cap
// under BOTH interpretations of the 2nd launch_bounds arg (R3 lesson: 512thr/2 gave 128).
__global__ __launch_bounds__(256, 1) void lstm_kernel(const float* __restrict__ xp,
                                                      const uint32_t* __restrict__ wreg,
                                                      const uint32_t* __restrict__ wtail,
                                                      float* __restrict__ hT) {
    int blk = blockIdx.x;
    int dir = blk >> 2, batch = blk & 3;
    int t = threadIdx.x;                      // cell index 0..255
    uint32_t w0[96], w1[96], w2[96], w3[96];  // gate i,f,g,o weights, cols 0..191
    {
        const uint4* ra = (const uint4*)wreg + (size_t)dir * 24 * 1024;
#pragma unroll
        for (int i = 0; i < 24; ++i) {
            uint4 v = ra[i * 1024 + t];
            w0[i * 4 + 0] = v.x; w0[i * 4 + 1] = v.y; w0[i * 4 + 2] = v.z; w0[i * 4 + 3] = v.w;
        }
#pragma unroll
        for (int i = 0; i < 24; ++i) {
            uint4 v = ra[i * 1024 + 256 + t];
            w1[i * 4 + 0] = v.x; w1[i * 4 + 1] = v.y; w1[i * 4 + 2] = v.z; w1[i * 4 + 3] = v.w;
        }
#pragma unroll
        for (int i = 0; i < 24; ++i) {
            uint4 v = ra[i * 1024 + 512 + t];
            w2[i * 4 + 0] = v.x; w2[i * 4 + 1] = v.y; w2[i * 4 + 2] = v.z; w2[i * 4 + 3] = v.w;
        }
#pragma unroll
        for (int i = 0; i < 24; ++i) {
            uint4 v = ra[i * 1024 + 768 + t];
            w3[i * 4 + 0] = v.x; w3[i * 4 + 1] = v.y; w3[i * 4 + 2] = v.z; w3[i * 4 + 3] = v.w;
        }
    }
    __shared__ uint32_t wlds[32 * 1024];      // 128 KB tail, [ku][row]
    __shared__ uint32_t h_pk[128];            // h as 128 half2 pairs
    {
        const uint32_t* tsrc = wtail + (size_t)dir * 32 * 1024;
        for (int i = t; i < 32 * 1024; i += 256) wlds[i] = tsrc[i];
    }
    if (t < 128) h_pk[t] = 0;
    __syncthreads();
    float creg = 0.f;
    const float* xpb = xp + dir * 131072 + batch * 1024;
#pragma unroll 1
    for (int step = 0; step < 32; ++step) {
        int teff = dir ? (31 - step) : step;
        float x0 = xpb[teff * 4096 + t];
        float x1 = xpb[teff * 4096 + 256 + t];
        float x2 = xpb[teff * 4096 + 512 + t];
        float x3 = xpb[teff * 4096 + 768 + t];
        float a0 = 0.f, a1 = 0.f, a2 = 0.f, a3 = 0.f;
#pragma unroll
        for (int q = 0; q < 24; ++q) {
            uint4 hq = *(const uint4*)&h_pk[q * 4];   // broadcast read
            a0 = dot2(w0[q * 4 + 0], hq.x, a0); a0 = dot2(w0[q * 4 + 1], hq.y, a0);
            a0 = dot2(w0[q * 4 + 2], hq.z, a0); a0 = dot2(w0[q * 4 + 3], hq.w, a0);
            a1 = dot2(w1[q * 4 + 0], hq.x, a1); a1 = dot2(w1[q * 4 + 1], hq.y, a1);
            a1 = dot2(w1[q * 4 + 2], hq.z, a1); a1 = dot2(w1[q * 4 + 3], hq.w, a1);
            a2 = dot2(w2[q * 4 + 0], hq.x, a2); a2 = dot2(w2[q * 4 + 1], hq.y, a2);
            a2 = dot2(w2[q * 4 + 2], hq.z, a2); a2 = dot2(w2[q * 4 + 3], hq.w, a2);
            a3 = dot2(w3[q * 4 + 0], hq.x, a3); a3 = dot2(w3[q * 4 + 1], hq.y, a3);
            a3 = dot2(w3[q * 4 + 2], hq.z, a3); a3 = dot2(w3[q * 4 + 3], hq.w, a3);
        }
#pragma unroll
        for (int ku = 0; ku < 32; ++ku) {
            uint32_t hq = h_pk[96 + ku];              // broadcast read
            a0 = dot2(wlds[ku * 1024 + t], hq, a0);
            a1 = dot2(wlds[ku * 1024 + 256 + t], hq, a1);
            a2 = dot2(wlds[ku * 1024 + 512 + t], hq, a2);
            a3 = dot2(wlds[ku * 1024 + 768 + t], hq, a3);
        }
        float iv = a0 + x0, fv = a1 + x1, gg = a2 + x2, ov = a3 + x3;
        creg = sigf(fv) * creg + sigf(iv) * tanhfast(gg);
        float hv = sigf(ov) * tanhfast(creg);
        if (step == 31) hT[(size_t)(dir * 4 + batch) * 256 + t] = hv;
        __syncthreads();                              // all h_pk reads done
        float hnext = __shfl_down(hv, 1, 64);
        if ((t & 1) == 0) h_pk[t >> 1] = packh2(hv, hnext);
        __syncthreads();                              // h_pk ready for next step
    }
}

// ---------------- heads: mu/logvar/pi from concat(h_f, h_b) ----------------
__global__ __launch_bounds__(256) void heads_kernel(const float* __restrict__ hT,
                                                    const float* __restrict__ Wmu, const float* __restrict__ bmu,
                                                    const float* __restrict__ Wlv, const float* __restrict__ blv,
                                                    const float* __restrict__ Wpi, const float* __restrict__ bpi,
                                                    float* __restrict__ out) {
    __shared__ __align__(16) float feat[4][512];
    int tid = threadIdx.x;
    for (int i = tid; i < 2048; i += 256) {
        int b = i >> 9, j = i & 511;
        int d = j >> 8, jj = j & 255;
        feat[b][j] = hT[(size_t)(d * 4 + b) * 256 + jj];
    }
    __syncthreads();
    int o = blockIdx.x * 256 + tid;
    if (o >= 4128) return;
    const float* Wr;
    float bv;
    int kind, m;
    if (o < 2048) { Wr = Wmu + (size_t)o * 512; bv = bmu[o]; kind = 0; m = o; }
    else if (o < 4096) { m = o - 2048; Wr = Wlv + (size_t)m * 512; bv = blv[m]; kind = 1; }
    else { m = o - 4096; Wr = Wpi + (size_t)m * 512; bv = bpi[m]; kind = 2; }
    float s0 = bv, s1 = bv, s2 = bv, s3 = bv;
    for (int k = 0; k < 512; k += 4) {
        float4 wv = *(const float4*)(Wr + k);
        s0 += feat[0][k] * wv.x + feat[0][k + 1] * wv.y + feat[0][k + 2] * wv.z + feat[0][k + 3] * wv.w;
        s1 += feat[1][k] * wv.x + feat[1][k + 1] * wv.y + feat[1][k + 2] * wv.z + feat[1][k + 3] * wv.w;
        s2 += feat[2][k] * wv.x + feat[2][k + 1] * wv.y + feat[2][k + 2] * wv.z + feat[2][k + 3] * wv.w;
        s3 += feat[3][k] * wv.x + feat[3][k + 1] * wv.y + feat[3][k + 2] * wv.z + feat[3][k + 3] * wv.w;
    }
    if (kind == 0) {
        out[0 * 2048 + m] = s0; out[1 * 2048 + m] = s1; out[2 * 2048 + m] = s2; out[3 * 2048 + m] = s3;
    } else if (kind == 1) {
        out[8192 + 0 * 2048 + m] = s0; out[8192 + 1 * 2048 + m] = s1;
        out[8192 + 2 * 2048 + m] = s2; out[8192 + 3 * 2048 + m] = s3;
    } else {
        out[16384 + 0 * 32 + m] = s0; out[16384 + 1 * 32 + m] = s1;
        out[16384 + 2 * 32 + m] = s2; out[16384 + 3 * 32 + m] = s3;
    }
}

extern "C" void kernel_launch(void* const* d_in, const int* in_sizes, int n_in,
                              void* d_out, int out_size, void* d_ws, size_t ws_size,
                              hipStream_t stream) {
    const float* x = (const float*)d_in[0];
    const int* ei = (const int*)d_in[1];
    const float* W1 = (const float*)d_in[2];
    const float* as1 = (const float*)d_in[3];
    const float* ad1 = (const float*)d_in[4];
    const float* b1 = (const float*)d_in[5];
    const float* W2 = (const float*)d_in[6];
    const float* as2 = (const float*)d_in[7];
    const float* ad2 = (const float*)d_in[8];
    const float* b2 = (const float*)d_in[9];
    const float* W3 = (const float*)d_in[10];
    const float* as3 = (const float*)d_in[11];
    const float* ad3 = (const float*)d_in[12];
    const float* b3 = (const float*)d_in[13];
    const float* Wih_f = (const float*)d_in[14];
    const float* Whh_f = (const float*)d_in[15];
    const float* bih_f = (const float*)d_in[16];
    const float* bhh_f = (const float*)d_in[17];
    const float* Wih_b = (const float*)d_in[18];
    const float* Whh_b = (const float*)d_in[19];
    const float* bih_b = (const float*)d_in[20];
    const float* bhh_b = (const float*)d_in[21];
    const float* Wmu = (const float*)d_in[22];
    const float* bmu = (const float*)d_in[23];
    const float* Wlv = (const float*)d_in[24];
    const float* blv = (const float*)d_in[25];
    const float* Wpi = (const float*)d_in[26];
    const float* bpi = (const float*)d_in[27];

    float* ws = (float*)d_ws;
    float* bufA = ws;                    // 4,194,304 f32 (feature buffer)
    float* bufB = ws + 4194304;          // 4,194,304 f32 (output buffer)
    float* asb = ws + 8388608;           // 65,536
    float* adb = ws + 8454144;           // 65,536
    int* cnt = (int*)(ws + 8519680);     // 128 ints
    int* col = cnt + 128;                // 32,768 ints
    float* gemb = ws + 8552576;          // 8,192
    float* xp = ws + 8560768;            // 262,144
    float* hT = ws + 8822912;            // 2,048 (final h per dir x batch)
    uint32_t* wreg = (uint32_t*)ws;      // 196,608 u32 — overlaps bufA (dead by then)
    uint32_t* wtail = wreg + 196608;     // 65,536 u32
    float* out = (float*)d_out;

    build_csr_kernel<<<1, 1024, 0, stream>>>(ei, cnt, col);

    // GAT layer 1
    gemm_kernel<<<dim3(4, 256), 256, 0, stream>>>(x, W1, bufA, NNODE, 256, 64);
    att_kernel<4><<<4096, 256, 0, stream>>>(bufA, as1, ad1, asb, adb);
    agg_kernel<4><<<4096, 256, 0, stream>>>(bufA, asb, adb, cnt, col, b1, bufB);
    // GAT layer 2
    gemm_kernel<<<dim3(4, 256), 256, 0, stream>>>(bufB, W2, bufA, NNODE, 256, 256);
    att_kernel<4><<<4096, 256, 0, stream>>>(bufA, as2, ad2, asb, adb);
    agg_kernel<4><<<4096, 256, 0, stream>>>(bufA, asb, adb, cnt, col, b2, bufB);
    // GAT layer 3 (single head)
    gemm_kernel<<<dim3(1, 256), 256, 0, stream>>>(bufB, W3, bufA, NNODE, 64, 256);
    att_kernel<1><<<4096, 256, 0, stream>>>(bufA, as3, ad3, asb, adb);
    agg_kernel<1><<<4096, 256, 0, stream>>>(bufA, asb, adb, cnt, col, b3, bufB);
    // bufA dead from here on -> wreg/wtail may overwrite its first 1 MB
    wpack_kernel<<<8, 256, 0, stream>>>(Whh_f, Whh_b, wreg, wtail);
    // pool + BiLSTM + heads
    pool_kernel<<<128, 64, 0, stream>>>(bufB, gemb);
    xpart_kernel<<<128, 256, 0, stream>>>(gemb, Wih_f, bih_f, bhh_f, Wih_b, bih_b, bhh_b, xp);
    lstm_kernel<<<8, 256, 0, stream>>>(xp, wreg, wtail, hT);
    heads_kernel<<<17, 256, 0, stream>>>(hT, Wmu, bmu, Wlv, blv, Wpi, bpi, out);
}

// Round 5
// 420.241 us; speedup vs baseline: 1.2301x; 1.2301x over previous
//
#include <hip/hip_runtime.h>
#include <hip/hip_bf16.h>
#include <cstdint>

#define NLOC 128        // nodes per graph
#define NGRAPH 128      // bs*T
#define NNODE 16384     // total nodes
#define EBASE 2048      // base edges per graph
#define CSTRIDE 256     // csr col stride per local node

typedef _Float16 half2v __attribute__((ext_vector_type(2)));

__device__ __forceinline__ float sigf(float x) { return 1.f / (1.f + __expf(-x)); }
__device__ __forceinline__ float tanhfast(float x) {
    float e = __expf(2.f * x);
    return 1.f - 2.f / (e + 1.f);
}
__device__ __forceinline__ uint32_t packh2(float a, float b) {
    half2v v;
    v.x = (_Float16)a; v.y = (_Float16)b;
    return __builtin_bit_cast(uint32_t, v);
}
__device__ __forceinline__ float dot2(uint32_t w, uint32_t h, float acc) {
#if __has_builtin(__builtin_amdgcn_fdot2)
    return __builtin_amdgcn_fdot2(__builtin_bit_cast(half2v, w),
                                  __builtin_bit_cast(half2v, h), acc, false);
#else
    half2v wv = __builtin_bit_cast(half2v, w);
    half2v hv = __builtin_bit_cast(half2v, h);
    return acc + (float)wv.x * (float)hv.x + (float)wv.y * (float)hv.y;
#endif
}

// ---------------- CSR of the shared per-graph edge list (dst -> list of src) ----------------
__global__ __launch_bounds__(1024) void build_csr_kernel(const int* __restrict__ ei,
                                                         int* __restrict__ cnt,
                                                         int* __restrict__ col) {
    __shared__ int c8[NLOC][8];
    int tid = threadIdx.x;
    int v = tid >> 3, p = tid & 7;
    const int* srcs = ei;
    const int* dsts = ei + EBASE;
    int e0 = p * 256, e1 = e0 + 256;
    int c = 0;
    for (int e = e0; e < e1; ++e) c += (dsts[e] == v);
    c8[v][p] = c;
    __syncthreads();
    int start = 0;
    for (int q = 0; q < p; ++q) start += c8[v][q];
    if (p == 0) {
        int tot = 0;
        for (int q = 0; q < 8; ++q) tot += c8[v][q];
        cnt[v] = tot;
    }
    int w = start;
    for (int e = e0; e < e1; ++e)
        if (dsts[e] == v) col[v * CSTRIDE + (w++)] = srcs[e];
}

// ---------------- fp32 tiled GEMM: C[M,N] = A[M,K] @ B[K,N]; M%64==0, N%64==0, K%16==0 ----
__global__ __launch_bounds__(256) void gemm_kernel(const float* __restrict__ A,
                                                   const float* __restrict__ B,
                                                   float* __restrict__ C,
                                                   int M, int N, int K) {
    __shared__ __align__(16) float As[16][64];
    __shared__ __align__(16) float Bs[16][64];
    int tid = threadIdx.x;
    int bm = blockIdx.y, bn = blockIdx.x;
    int am = tid >> 2, ak = (tid & 3) << 2;
    int bk = tid >> 4, bn4 = (tid & 15) << 2;
    int ty = tid >> 4, tx = tid & 15;
    const float* Ab = A + (size_t)bm * 64 * K;
    const float* Bb = B + bn * 64;
    float acc[4][4] = {};
    for (int k0 = 0; k0 < K; k0 += 16) {
        float4 av = *(const float4*)(Ab + (size_t)am * K + k0 + ak);
        float4 bv = *(const float4*)(Bb + (size_t)(k0 + bk) * N + bn4);
        As[ak + 0][am] = av.x; As[ak + 1][am] = av.y;
        As[ak + 2][am] = av.z; As[ak + 3][am] = av.w;
        *(float4*)&Bs[bk][bn4] = bv;
        __syncthreads();
#pragma unroll
        for (int kk = 0; kk < 16; ++kk) {
            float4 a4 = *(const float4*)&As[kk][ty << 2];
            float4 b4 = *(const float4*)&Bs[kk][tx << 2];
            acc[0][0] += a4.x * b4.x; acc[0][1] += a4.x * b4.y; acc[0][2] += a4.x * b4.z; acc[0][3] += a4.x * b4.w;
            acc[1][0] += a4.y * b4.x; acc[1][1] += a4.y * b4.y; acc[1][2] += a4.y * b4.z; acc[1][3] += a4.y * b4.w;
            acc[2][0] += a4.z * b4.x; acc[2][1] += a4.z * b4.y; acc[2][2] += a4.z * b4.z; acc[2][3] += a4.z * b4.w;
            acc[3][0] += a4.w * b4.x; acc[3][1] += a4.w * b4.y; acc[3][2] += a4.w * b4.z; acc[3][3] += a4.w * b4.w;
        }
        __syncthreads();
    }
    float* Cb = C + (size_t)(bm * 64 + ty * 4) * N + bn * 64 + tx * 4;
#pragma unroll
    for (int i = 0; i < 4; ++i)
        *(float4*)(Cb + (size_t)i * N) = make_float4(acc[i][0], acc[i][1], acc[i][2], acc[i][3]);
}

// ---------------- attention dot products per node ----------------
template <int H>
__global__ __launch_bounds__(256) void att_kernel(const float* __restrict__ hf,
                                                  const float* __restrict__ a_s,
                                                  const float* __restrict__ a_d,
                                                  float* __restrict__ asb,
                                                  float* __restrict__ adb) {
    int lane = threadIdx.x & 63;
    int n = blockIdx.x * 4 + (threadIdx.x >> 6);
    const float* row = hf + (size_t)n * (H * 64);
#pragma unroll
    for (int h = 0; h < H; ++h) {
        float v = row[h * 64 + lane];
        float ps = v * a_s[h * 64 + lane];
        float pd = v * a_d[h * 64 + lane];
#pragma unroll
        for (int off = 32; off > 0; off >>= 1) {
            ps += __shfl_xor(ps, off, 64);
            pd += __shfl_xor(pd, off, 64);
        }
        if (lane == 0) { asb[n * H + h] = ps; adb[n * H + h] = pd; }
    }
}

// ---------------- GAT aggregation: softmax over in-edges, gather, +bias, ReLU -------------
template <int H>
__global__ __launch_bounds__(256) void agg_kernel(const float* __restrict__ hf,
                                                  const float* __restrict__ asb,
                                                  const float* __restrict__ adb,
                                                  const int* __restrict__ cnt,
                                                  const int* __restrict__ col,
                                                  const float* __restrict__ bias,
                                                  float* __restrict__ out) {
    __shared__ float e_lds[4][96][H];
    __shared__ int u_lds[4][96];
    int lane = threadIdx.x & 63, w = threadIdx.x >> 6;
    int n = blockIdx.x * 4 + w;
    int v = n & 127, base = n & ~127;
    int deg = cnt[v];
    int tot = min(deg + 1, 96);
    float adst[H];
#pragma unroll
    for (int h = 0; h < H; ++h) adst[h] = adb[n * H + h];
    for (int k = lane; k < tot; k += 64) {
        int u = (k < deg) ? col[v * CSTRIDE + k] : v;
        u_lds[w][k] = u;
#pragma unroll
        for (int h = 0; h < H; ++h) {
            float e = asb[(base + u) * H + h] + adst[h];
            e_lds[w][k][h] = (e > 0.f) ? e : 0.2f * e;
        }
    }
    __syncthreads();
    float m[H];
#pragma unroll
    for (int h = 0; h < H; ++h) m[h] = -1e30f;
    for (int k = 0; k < tot; ++k)
#pragma unroll
        for (int h = 0; h < H; ++h) m[h] = fmaxf(m[h], e_lds[w][k][h]);
    __syncthreads();
    for (int k = lane; k < tot; k += 64)
#pragma unroll
        for (int h = 0; h < H; ++h) e_lds[w][k][h] = __expf(e_lds[w][k][h] - m[h]);
    __syncthreads();
    float den[H], acc[H];
#pragma unroll
    for (int h = 0; h < H; ++h) { den[h] = 0.f; acc[h] = 0.f; }
    for (int k = 0; k < tot; ++k) {
        int u = u_lds[w][k];
        const float* hr = hf + (size_t)(base + u) * (H * 64);
#pragma unroll
        for (int h = 0; h < H; ++h) {
            float wgt = e_lds[w][k][h];
            den[h] += wgt;
            acc[h] += wgt * hr[h * 64 + lane];
        }
    }
#pragma unroll
    for (int h = 0; h < H; ++h) {
        float o = acc[h] / (den[h] + 1e-16f) + bias[h * 64 + lane];
        out[(size_t)n * (H * 64) + h * 64 + lane] = fmaxf(o, 0.f);
    }
}

// ---------------- graph sum-pool into sequence layout [t*4+b][64] ----------------
__global__ void pool_kernel(const float* __restrict__ h, float* __restrict__ gemb) {
    int g = blockIdx.x;       // g = b*32 + t
    int c = threadIdx.x;      // 64 threads
    int b = g >> 5, t = g & 31;
    float s = 0.f;
    const float* p = h + (size_t)g * 128 * 64 + c;
    for (int vv = 0; vv < 128; ++vv) s += p[vv * 64];
    gemb[(t * 4 + b) * 64 + c] = s;
}

// ---------------- LSTM input part: xp[dir][r][o] = seq[r] . Wih[o] + bih[o] + bhh[o] ------
__global__ __launch_bounds__(256) void xpart_kernel(const float* __restrict__ gemb,
                                                    const float* __restrict__ Wf, const float* __restrict__ bif, const float* __restrict__ bhf,
                                                    const float* __restrict__ Wb, const float* __restrict__ bib, const float* __restrict__ bhb,
                                                    float* __restrict__ xp) {
    __shared__ float a[64];
    int r = blockIdx.x, tid = threadIdx.x;
    if (tid < 64) a[tid] = gemb[r * 64 + tid];
    __syncthreads();
    for (int dir = 0; dir < 2; ++dir) {
        const float* W = dir ? Wb : Wf;
        const float* bi = dir ? bib : bif;
        const float* bh = dir ? bhb : bhf;
        for (int o = tid; o < 1024; o += 256) {
            const float* wr = W + (size_t)o * 64;
            float s = bi[o] + bh[o];
#pragma unroll
            for (int k = 0; k < 64; k += 4) {
                float4 wv = *(const float4*)(wr + k);
                s += a[k] * wv.x + a[k + 1] * wv.y + a[k + 2] * wv.z + a[k + 3] * wv.w;
            }
            xp[dir * 131072 + r * 1024 + o] = s;
        }
    }
}

// ---------------- pre-pack Whh to f16 pairs: reg part [dir][chunk i][row] (uint4),
//                  tail part transposed [dir][ku][row] (u32) ----------------
__global__ __launch_bounds__(256) void wpack_kernel(const float* __restrict__ Whh_f,
                                                    const float* __restrict__ Whh_b,
                                                    uint32_t* __restrict__ wreg,
                                                    uint32_t* __restrict__ wtail) {
    int gid = blockIdx.x * 256 + threadIdx.x;   // 0..2047
    int dir = gid >> 10, row = gid & 1023;
    const float* src = (dir ? Whh_b : Whh_f) + (size_t)row * 256;
    // cols 0..191 -> 24 uint4 chunks (8 cols each), coalesced-by-row layout
    uint4* wr4 = (uint4*)wreg;
#pragma unroll
    for (int i = 0; i < 24; ++i) {
        uint4 v;
        v.x = packh2(src[i * 8 + 0], src[i * 8 + 1]);
        v.y = packh2(src[i * 8 + 2], src[i * 8 + 3]);
        v.z = packh2(src[i * 8 + 4], src[i * 8 + 5]);
        v.w = packh2(src[i * 8 + 6], src[i * 8 + 7]);
        wr4[(size_t)(dir * 24 + i) * 1024 + row] = v;
    }
    // cols 192..255 -> 32 u32, transposed [ku][row]
#pragma unroll
    for (int ku = 0; ku < 32; ++ku) {
        wtail[(size_t)(dir * 32 + ku) * 1024 + row] =
            packh2(src[192 + ku * 2], src[192 + ku * 2 + 1]);
    }
}

// ---------------- BiLSTM recurrent: 8 blocks (dir x batch), 512 threads ------------------
// Thread t owns rows t and t+512. For t<256 that is (i-gate, g-gate) of cell t; for t>=256
// it is (f-gate, o-gate) of cell t-256. Threads >=256 publish (f,o) as one float2; threads
// <256 do the thread-local c/h update. Weights: cols 0..191 in 2x96 VGPRs (f16 pairs,
// v_dot2), cols 192..255 in LDS [ku][row] (conflict-free b32, 0 conflicts measured R3/R4).
// __launch_bounds__(512,1): 8 waves/block -> 2 waves/SIMD -> 256-VGPR tier; need ~220.
// (R3 lesson: (512,2) forced the 128 tier and spilled; R4 lesson: >256 arch VGPRs is
// impossible for VALU code, so 4-rows/thread can never be register-resident.)
__global__ __launch_bounds__(512, 1) void lstm_kernel(const float* __restrict__ xp,
                                                      const uint32_t* __restrict__ wreg,
                                                      const uint32_t* __restrict__ wtail,
                                                      float* __restrict__ hT) {
    int blk = blockIdx.x;
    int dir = blk >> 2, batch = blk & 3;
    int t = threadIdx.x;                      // rows t, t+512
    uint32_t wa[96], wb[96];
    {
        const uint4* ra = (const uint4*)wreg + (size_t)dir * 24 * 1024;
#pragma unroll
        for (int i = 0; i < 24; ++i) {
            uint4 v = ra[i * 1024 + t];
            wa[i * 4 + 0] = v.x; wa[i * 4 + 1] = v.y; wa[i * 4 + 2] = v.z; wa[i * 4 + 3] = v.w;
        }
#pragma unroll
        for (int i = 0; i < 24; ++i) {
            uint4 v = ra[i * 1024 + 512 + t];
            wb[i * 4 + 0] = v.x; wb[i * 4 + 1] = v.y; wb[i * 4 + 2] = v.z; wb[i * 4 + 3] = v.w;
        }
    }
    __shared__ uint32_t wlds[32 * 1024];      // 128 KB tail weights, [ku][row]
    __shared__ uint32_t h_pk[128];            // h as 128 half2 pairs
    __shared__ __align__(8) float2 fo_lds[256];
    {
        const uint32_t* tsrc = wtail + (size_t)dir * 32 * 1024;
        for (int i = t; i < 32 * 1024; i += 512) wlds[i] = tsrc[i];
    }
    if (t < 128) h_pk[t] = 0;
    __syncthreads();
    float creg = 0.f;
    const float* xpb = xp + dir * 131072 + batch * 1024;
#pragma unroll 1
    for (int step = 0; step < 32; ++step) {
        int teff = dir ? (31 - step) : step;
        float xa = xpb[teff * 4096 + t];
        float xb = xpb[teff * 4096 + 512 + t];
        float acca = 0.f, accb = 0.f;
#pragma unroll
        for (int q = 0; q < 24; ++q) {
            uint4 hq = *(const uint4*)&h_pk[q * 4];   // same-address broadcast
            acca = dot2(wa[q * 4 + 0], hq.x, acca);
            acca = dot2(wa[q * 4 + 1], hq.y, acca);
            acca = dot2(wa[q * 4 + 2], hq.z, acca);
            acca = dot2(wa[q * 4 + 3], hq.w, acca);
            accb = dot2(wb[q * 4 + 0], hq.x, accb);
            accb = dot2(wb[q * 4 + 1], hq.y, accb);
            accb = dot2(wb[q * 4 + 2], hq.z, accb);
            accb = dot2(wb[q * 4 + 3], hq.w, accb);
        }
#pragma unroll
        for (int ku = 0; ku < 32; ++ku) {
            uint32_t hq = h_pk[96 + ku];              // same-address broadcast
            acca = dot2(wlds[ku * 1024 + t], hq, acca);
            accb = dot2(wlds[ku * 1024 + 512 + t], hq, accb);
        }
        float ga = acca + xa;                 // t<256: i-gate; t>=256: f-gate
        float gb = accb + xb;                 // t<256: g-gate; t>=256: o-gate
        if (t >= 256) fo_lds[t - 256] = make_float2(ga, gb);
        __syncthreads();
        if (t < 256) {
            float2 fo = fo_lds[t];
            creg = sigf(fo.x) * creg + sigf(ga) * tanhfast(gb);
            float hv = sigf(fo.y) * tanhfast(creg);
            if (step == 31) hT[(size_t)(dir * 4 + batch) * 256 + t] = hv;
            float hnext = __shfl_down(hv, 1, 64);
            if ((t & 1) == 0) h_pk[t >> 1] = packh2(hv, hnext);
        }
        __syncthreads();
    }
}

// ---------------- heads: mu/logvar/pi from concat(h_f, h_b) ----------------
__global__ __launch_bounds__(256) void heads_kernel(const float* __restrict__ hT,
                                                    const float* __restrict__ Wmu, const float* __restrict__ bmu,
                                                    const float* __restrict__ Wlv, const float* __restrict__ blv,
                                                    const float* __restrict__ Wpi, const float* __restrict__ bpi,
                                                    float* __restrict__ out) {
    __shared__ __align__(16) float feat[4][512];
    int tid = threadIdx.x;
    for (int i = tid; i < 2048; i += 256) {
        int b = i >> 9, j = i & 511;
        int d = j >> 8, jj = j & 255;
        feat[b][j] = hT[(size_t)(d * 4 + b) * 256 + jj];
    }
    __syncthreads();
    int o = blockIdx.x * 256 + tid;
    if (o >= 4128) return;
    const float* Wr;
    float bv;
    int kind, m;
    if (o < 2048) { Wr = Wmu + (size_t)o * 512; bv = bmu[o]; kind = 0; m = o; }
    else if (o < 4096) { m = o - 2048; Wr = Wlv + (size_t)m * 512; bv = blv[m]; kind = 1; }
    else { m = o - 4096; Wr = Wpi + (size_t)m * 512; bv = bpi[m]; kind = 2; }
    float s0 = bv, s1 = bv, s2 = bv, s3 = bv;
    for (int k = 0; k < 512; k += 4) {
        float4 wv = *(const float4*)(Wr + k);
        s0 += feat[0][k] * wv.x + feat[0][k + 1] * wv.y + feat[0][k + 2] * wv.z + feat[0][k + 3] * wv.w;
        s1 += feat[1][k] * wv.x + feat[1][k + 1] * wv.y + feat[1][k + 2] * wv.z + feat[1][k + 3] * wv.w;
        s2 += feat[2][k] * wv.x + feat[2][k + 1] * wv.y + feat[2][k + 2] * wv.z + feat[2][k + 3] * wv.w;
        s3 += feat[3][k] * wv.x + feat[3][k + 1] * wv.y + feat[3][k + 2] * wv.z + feat[3][k + 3] * wv.w;
    }
    if (kind == 0) {
        out[0 * 2048 + m] = s0; out[1 * 2048 + m] = s1; out[2 * 2048 + m] = s2; out[3 * 2048 + m] = s3;
    } else if (kind == 1) {
        out[8192 + 0 * 2048 + m] = s0; out[8192 + 1 * 2048 + m] = s1;
        out[8192 + 2 * 2048 + m] = s2; out[8192 + 3 * 2048 + m] = s3;
    } else {
        out[16384 + 0 * 32 + m] = s0; out[16384 + 1 * 32 + m] = s1;
        out[16384 + 2 * 32 + m] = s2; out[16384 + 3 * 32 + m] = s3;
    }
}

extern "C" void kernel_launch(void* const* d_in, const int* in_sizes, int n_in,
                              void* d_out, int out_size, void* d_ws, size_t ws_size,
                              hipStream_t stream) {
    const float* x = (const float*)d_in[0];
    const int* ei = (const int*)d_in[1];
    const float* W1 = (const float*)d_in[2];
    const float* as1 = (const float*)d_in[3];
    const float* ad1 = (const float*)d_in[4];
    const float* b1 = (const float*)d_in[5];
    const float* W2 = (const float*)d_in[6];
    const float* as2 = (const float*)d_in[7];
    const float* ad2 = (const float*)d_in[8];
    const float* b2 = (const float*)d_in[9];
    const float* W3 = (const float*)d_in[10];
    const float* as3 = (const float*)d_in[11];
    const float* ad3 = (const float*)d_in[12];
    const float* b3 = (const float*)d_in[13];
    const float* Wih_f = (const float*)d_in[14];
    const float* Whh_f = (const float*)d_in[15];
    const float* bih_f = (const float*)d_in[16];
    const float* bhh_f = (const float*)d_in[17];
    const float* Wih_b = (const float*)d_in[18];
    const float* Whh_b = (const float*)d_in[19];
    const float* bih_b = (const float*)d_in[20];
    const float* bhh_b = (const float*)d_in[21];
    const float* Wmu = (const float*)d_in[22];
    const float* bmu = (const float*)d_in[23];
    const float* Wlv = (const float*)d_in[24];
    const float* blv = (const float*)d_in[25];
    const float* Wpi = (const float*)d_in[26];
    const float* bpi = (const float*)d_in[27];

    float* ws = (float*)d_ws;
    float* bufA = ws;                    // 4,194,304 f32 (feature buffer)
    float* bufB = ws + 4194304;          // 4,194,304 f32 (output buffer)
    float* asb = ws + 8388608;           // 65,536
    float* adb = ws + 8454144;           // 65,536
    int* cnt = (int*)(ws + 8519680);     // 128 ints
    int* col = cnt + 128;                // 32,768 ints
    float* gemb = ws + 8552576;          // 8,192
    float* xp = ws + 8560768;            // 262,144
    float* hT = ws + 8822912;            // 2,048 (final h per dir x batch)
    uint32_t* wreg = (uint32_t*)ws;      // 196,608 u32 — overlaps bufA (dead by then)
    uint32_t* wtail = wreg + 196608;     // 65,536 u32
    float* out = (float*)d_out;

    build_csr_kernel<<<1, 1024, 0, stream>>>(ei, cnt, col);

    // GAT layer 1
    gemm_kernel<<<dim3(4, 256), 256, 0, stream>>>(x, W1, bufA, NNODE, 256, 64);
    att_kernel<4><<<4096, 256, 0, stream>>>(bufA, as1, ad1, asb, adb);
    agg_kernel<4><<<4096, 256, 0, stream>>>(bufA, asb, adb, cnt, col, b1, bufB);
    // GAT layer 2
    gemm_kernel<<<dim3(4, 256), 256, 0, stream>>>(bufB, W2, bufA, NNODE, 256, 256);
    att_kernel<4><<<4096, 256, 0, stream>>>(bufA, as2, ad2, asb, adb);
    agg_kernel<4><<<4096, 256, 0, stream>>>(bufA, asb, adb, cnt, col, b2, bufB);
    // GAT layer 3 (single head)
    gemm_kernel<<<dim3(1, 256), 256, 0, stream>>>(bufB, W3, bufA, NNODE, 64, 256);
    att_kernel<1><<<4096, 256, 0, stream>>>(bufA, as3, ad3, asb, adb);
    agg_kernel<1><<<4096, 256, 0, stream>>>(bufA, asb, adb, cnt, col, b3, bufB);
    // bufA dead from here on -> wreg/wtail may overwrite its first 1 MB
    wpack_kernel<<<8, 256, 0, stream>>>(Whh_f, Whh_b, wreg, wtail);
    // pool + BiLSTM + heads
    pool_kernel<<<128, 64, 0, stream>>>(bufB, gemb);
    xpart_kernel<<<128, 256, 0, stream>>>(gemb, Wih_f, bih_f, bhh_f, Wih_b, bih_b, bhh_b, xp);
    lstm_kernel<<<8, 512, 0, stream>>>(xp, wreg, wtail, hT);
    heads_kernel<<<17, 256, 0, stream>>>(hT, Wmu, bmu, Wlv, blv, Wpi, bpi, out);
}

// Round 6
// 394.020 us; speedup vs baseline: 1.3120x; 1.0665x over previous
//
#include <hip/hip_runtime.h>
#include <hip/hip_bf16.h>
#include <cstdint>

#define NLOC 128        // nodes per graph
#define NGRAPH 128      // bs*T
#define NNODE 16384     // total nodes
#define EBASE 2048      // base edges per graph
#define CSTRIDE 256     // csr col stride per local node

typedef _Float16 half2v __attribute__((ext_vector_type(2)));

__device__ __forceinline__ float sigf(float x) { return 1.f / (1.f + __expf(-x)); }
__device__ __forceinline__ float tanhfast(float x) {
    float e = __expf(2.f * x);
    return 1.f - 2.f / (e + 1.f);
}
__device__ __forceinline__ uint32_t packh2(float a, float b) {
    half2v v;
    v.x = (_Float16)a; v.y = (_Float16)b;
    return __builtin_bit_cast(uint32_t, v);
}
__device__ __forceinline__ float dot2(uint32_t w, uint32_t h, float acc) {
#if __has_builtin(__builtin_amdgcn_fdot2)
    return __builtin_amdgcn_fdot2(__builtin_bit_cast(half2v, w),
                                  __builtin_bit_cast(half2v, h), acc, false);
#else
    half2v wv = __builtin_bit_cast(half2v, w);
    half2v hv = __builtin_bit_cast(half2v, h);
    return acc + (float)wv.x * (float)hv.x + (float)wv.y * (float)hv.y;
#endif
}

// ---------------- CSR of the shared per-graph edge list (dst -> list of src) ----------------
__global__ __launch_bounds__(1024) void build_csr_kernel(const int* __restrict__ ei,
                                                         int* __restrict__ cnt,
                                                         int* __restrict__ col) {
    __shared__ int c8[NLOC][8];
    int tid = threadIdx.x;
    int v = tid >> 3, p = tid & 7;
    const int* srcs = ei;
    const int* dsts = ei + EBASE;
    int e0 = p * 256, e1 = e0 + 256;
    int c = 0;
    for (int e = e0; e < e1; ++e) c += (dsts[e] == v);
    c8[v][p] = c;
    __syncthreads();
    int start = 0;
    for (int q = 0; q < p; ++q) start += c8[v][q];
    if (p == 0) {
        int tot = 0;
        for (int q = 0; q < 8; ++q) tot += c8[v][q];
        cnt[v] = tot;
    }
    int w = start;
    for (int e = e0; e < e1; ++e)
        if (dsts[e] == v) col[v * CSTRIDE + (w++)] = srcs[e];
}

// ---------------- fp32 GEMM 128x128 tile, 8x8 micro-tile: C[M,N]=A@B; M%128==0,N%128==0,K%16==0
__global__ __launch_bounds__(256) void gemm128_kernel(const float* __restrict__ A,
                                                      const float* __restrict__ B,
                                                      float* __restrict__ C,
                                                      int M, int N, int K) {
    __shared__ __align__(16) float As[16][128];   // [k][m]
    __shared__ __align__(16) float Bs[16][128];   // [k][n]
    int tid = threadIdx.x;
    int bm = blockIdx.y, bn = blockIdx.x;
    int ar = tid >> 1, ak = (tid & 1) * 8;        // A: row ar, k-offset ak
    int bk = tid >> 4, bc = (tid & 15) * 8;       // B: k-row bk, col bc
    int ty = tid >> 4, tx = tid & 15;             // output 8x8 at (ty*8, tx*8)
    const float* Ab = A + (size_t)(bm * 128 + ar) * K;
    const float* Bb = B + (size_t)bn * 128 + bc;
    float acc[8][8] = {};
    for (int k0 = 0; k0 < K; k0 += 16) {
        float4 a0 = *(const float4*)(Ab + k0 + ak);
        float4 a1 = *(const float4*)(Ab + k0 + ak + 4);
        float4 b0 = *(const float4*)(Bb + (size_t)(k0 + bk) * N);
        float4 b1 = *(const float4*)(Bb + (size_t)(k0 + bk) * N + 4);
        As[ak + 0][ar] = a0.x; As[ak + 1][ar] = a0.y; As[ak + 2][ar] = a0.z; As[ak + 3][ar] = a0.w;
        As[ak + 4][ar] = a1.x; As[ak + 5][ar] = a1.y; As[ak + 6][ar] = a1.z; As[ak + 7][ar] = a1.w;
        *(float4*)&Bs[bk][bc] = b0;
        *(float4*)&Bs[bk][bc + 4] = b1;
        __syncthreads();
#pragma unroll
        for (int kk = 0; kk < 16; ++kk) {
            float4 x0 = *(const float4*)&As[kk][ty * 8];
            float4 x1 = *(const float4*)&As[kk][ty * 8 + 4];
            float4 y0 = *(const float4*)&Bs[kk][tx * 8];
            float4 y1 = *(const float4*)&Bs[kk][tx * 8 + 4];
            float xa[8] = {x0.x, x0.y, x0.z, x0.w, x1.x, x1.y, x1.z, x1.w};
            float yb[8] = {y0.x, y0.y, y0.z, y0.w, y1.x, y1.y, y1.z, y1.w};
#pragma unroll
            for (int i = 0; i < 8; ++i)
#pragma unroll
                for (int j = 0; j < 8; ++j) acc[i][j] += xa[i] * yb[j];
        }
        __syncthreads();
    }
    float* Cb = C + (size_t)(bm * 128 + ty * 8) * N + (size_t)bn * 128 + tx * 8;
#pragma unroll
    for (int i = 0; i < 8; ++i) {
        *(float4*)(Cb + (size_t)i * N) = make_float4(acc[i][0], acc[i][1], acc[i][2], acc[i][3]);
        *(float4*)(Cb + (size_t)i * N + 4) = make_float4(acc[i][4], acc[i][5], acc[i][6], acc[i][7]);
    }
}

// ---------------- fp32 tiled GEMM 64x64 (kept for N=64 layer-3) ----------------
__global__ __launch_bounds__(256) void gemm_kernel(const float* __restrict__ A,
                                                   const float* __restrict__ B,
                                                   float* __restrict__ C,
                                                   int M, int N, int K) {
    __shared__ __align__(16) float As[16][64];
    __shared__ __align__(16) float Bs[16][64];
    int tid = threadIdx.x;
    int bm = blockIdx.y, bn = blockIdx.x;
    int am = tid >> 2, ak = (tid & 3) << 2;
    int bk = tid >> 4, bn4 = (tid & 15) << 2;
    int ty = tid >> 4, tx = tid & 15;
    const float* Ab = A + (size_t)bm * 64 * K;
    const float* Bb = B + bn * 64;
    float acc[4][4] = {};
    for (int k0 = 0; k0 < K; k0 += 16) {
        float4 av = *(const float4*)(Ab + (size_t)am * K + k0 + ak);
        float4 bv = *(const float4*)(Bb + (size_t)(k0 + bk) * N + bn4);
        As[ak + 0][am] = av.x; As[ak + 1][am] = av.y;
        As[ak + 2][am] = av.z; As[ak + 3][am] = av.w;
        *(float4*)&Bs[bk][bn4] = bv;
        __syncthreads();
#pragma unroll
        for (int kk = 0; kk < 16; ++kk) {
            float4 a4 = *(const float4*)&As[kk][ty << 2];
            float4 b4 = *(const float4*)&Bs[kk][tx << 2];
            acc[0][0] += a4.x * b4.x; acc[0][1] += a4.x * b4.y; acc[0][2] += a4.x * b4.z; acc[0][3] += a4.x * b4.w;
            acc[1][0] += a4.y * b4.x; acc[1][1] += a4.y * b4.y; acc[1][2] += a4.y * b4.z; acc[1][3] += a4.y * b4.w;
            acc[2][0] += a4.z * b4.x; acc[2][1] += a4.z * b4.y; acc[2][2] += a4.z * b4.z; acc[2][3] += a4.z * b4.w;
            acc[3][0] += a4.w * b4.x; acc[3][1] += a4.w * b4.y; acc[3][2] += a4.w * b4.z; acc[3][3] += a4.w * b4.w;
        }
        __syncthreads();
    }
    float* Cb = C + (size_t)(bm * 64 + ty * 4) * N + bn * 64 + tx * 4;
#pragma unroll
    for (int i = 0; i < 4; ++i)
        *(float4*)(Cb + (size_t)i * N) = make_float4(acc[i][0], acc[i][1], acc[i][2], acc[i][3]);
}

// ---------------- attention dot products per node ----------------
template <int H>
__global__ __launch_bounds__(256) void att_kernel(const float* __restrict__ hf,
                                                  const float* __restrict__ a_s,
                                                  const float* __restrict__ a_d,
                                                  float* __restrict__ asb,
                                                  float* __restrict__ adb) {
    int lane = threadIdx.x & 63;
    int n = blockIdx.x * 4 + (threadIdx.x >> 6);
    const float* row = hf + (size_t)n * (H * 64);
#pragma unroll
    for (int h = 0; h < H; ++h) {
        float v = row[h * 64 + lane];
        float ps = v * a_s[h * 64 + lane];
        float pd = v * a_d[h * 64 + lane];
#pragma unroll
        for (int off = 32; off > 0; off >>= 1) {
            ps += __shfl_xor(ps, off, 64);
            pd += __shfl_xor(pd, off, 64);
        }
        if (lane == 0) { asb[n * H + h] = ps; adb[n * H + h] = pd; }
    }
}

// ---------------- GAT aggregation: softmax over in-edges, gather, +bias, ReLU -------------
template <int H>
__global__ __launch_bounds__(256) void agg_kernel(const float* __restrict__ hf,
                                                  const float* __restrict__ asb,
                                                  const float* __restrict__ adb,
                                                  const int* __restrict__ cnt,
                                                  const int* __restrict__ col,
                                                  const float* __restrict__ bias,
                                                  float* __restrict__ out) {
    __shared__ float e_lds[4][96][H];
    __shared__ int u_lds[4][96];
    int lane = threadIdx.x & 63, w = threadIdx.x >> 6;
    int n = blockIdx.x * 4 + w;
    int v = n & 127, base = n & ~127;
    int deg = cnt[v];
    int tot = min(deg + 1, 96);
    float adst[H];
#pragma unroll
    for (int h = 0; h < H; ++h) adst[h] = adb[n * H + h];
    for (int k = lane; k < tot; k += 64) {
        int u = (k < deg) ? col[v * CSTRIDE + k] : v;
        u_lds[w][k] = u;
#pragma unroll
        for (int h = 0; h < H; ++h) {
            float e = asb[(base + u) * H + h] + adst[h];
            e_lds[w][k][h] = (e > 0.f) ? e : 0.2f * e;
        }
    }
    __syncthreads();
    float m[H];
#pragma unroll
    for (int h = 0; h < H; ++h) m[h] = -1e30f;
    for (int k = 0; k < tot; ++k)
#pragma unroll
        for (int h = 0; h < H; ++h) m[h] = fmaxf(m[h], e_lds[w][k][h]);
    __syncthreads();
    for (int k = lane; k < tot; k += 64)
#pragma unroll
        for (int h = 0; h < H; ++h) e_lds[w][k][h] = __expf(e_lds[w][k][h] - m[h]);
    __syncthreads();
    float den[H], acc[H];
#pragma unroll
    for (int h = 0; h < H; ++h) { den[h] = 0.f; acc[h] = 0.f; }
    for (int k = 0; k < tot; ++k) {
        int u = u_lds[w][k];
        const float* hr = hf + (size_t)(base + u) * (H * 64);
#pragma unroll
        for (int h = 0; h < H; ++h) {
            float wgt = e_lds[w][k][h];
            den[h] += wgt;
            acc[h] += wgt * hr[h * 64 + lane];
        }
    }
#pragma unroll
    for (int h = 0; h < H; ++h) {
        float o = acc[h] / (den[h] + 1e-16f) + bias[h * 64 + lane];
        out[(size_t)n * (H * 64) + h * 64 + lane] = fmaxf(o, 0.f);
    }
}

// ---------------- fused pool + LSTM input part --------------------------------------------
// Block g (graph, b-major): sum-pool 128 nodes -> emb[64] in LDS, then
// xp[dir][r][o] = emb . Wih[o] + bih[o] + bhh[o] with r = (g&31)*4 + (g>>5).
__global__ __launch_bounds__(256) void poolx_kernel(const float* __restrict__ h,
                                                    const float* __restrict__ Wf, const float* __restrict__ bif, const float* __restrict__ bhf,
                                                    const float* __restrict__ Wb, const float* __restrict__ bib, const float* __restrict__ bhb,
                                                    float* __restrict__ xp) {
    __shared__ float part_l[4][64];
    __shared__ float emb[64];
    int g = blockIdx.x, tid = threadIdx.x;
    int c = tid & 63, prt = tid >> 6;
    {
        const float* p = h + (size_t)g * 8192 + prt * 32 * 64 + c;
        float s = 0.f;
#pragma unroll
        for (int vv = 0; vv < 32; ++vv) s += p[vv * 64];
        part_l[prt][c] = s;
    }
    __syncthreads();
    if (tid < 64) emb[tid] = part_l[0][tid] + part_l[1][tid] + part_l[2][tid] + part_l[3][tid];
    __syncthreads();
    int r = (g & 31) * 4 + (g >> 5);
    for (int dir = 0; dir < 2; ++dir) {
        const float* W = dir ? Wb : Wf;
        const float* bi = dir ? bib : bif;
        const float* bh = dir ? bhb : bhf;
        for (int o = tid; o < 1024; o += 256) {
            const float* wr = W + (size_t)o * 64;
            float s = bi[o] + bh[o];
#pragma unroll
            for (int k = 0; k < 64; k += 4) {
                float4 wv = *(const float4*)(wr + k);
                s += emb[k] * wv.x + emb[k + 1] * wv.y + emb[k + 2] * wv.z + emb[k + 3] * wv.w;
            }
            xp[dir * 131072 + r * 1024 + o] = s;
        }
    }
}

// ---------------- pre-pack Whh to f16 pairs: reg part [dir][i][row] uint4 (cols 0..191),
//                  tail part [dir][ku][row] uint4 (cols 192+8ku..199+8ku) ----------------
__global__ __launch_bounds__(256) void wpack_kernel(const float* __restrict__ Whh_f,
                                                    const float* __restrict__ Whh_b,
                                                    uint32_t* __restrict__ wreg,
                                                    uint32_t* __restrict__ wtail) {
    int gid = blockIdx.x * 256 + threadIdx.x;   // 0..2047
    int dir = gid >> 10, row = gid & 1023;
    const float* src = (dir ? Whh_b : Whh_f) + (size_t)row * 256;
    uint4* wr4 = (uint4*)wreg;
#pragma unroll
    for (int i = 0; i < 24; ++i) {
        uint4 v;
        v.x = packh2(src[i * 8 + 0], src[i * 8 + 1]);
        v.y = packh2(src[i * 8 + 2], src[i * 8 + 3]);
        v.z = packh2(src[i * 8 + 4], src[i * 8 + 5]);
        v.w = packh2(src[i * 8 + 6], src[i * 8 + 7]);
        wr4[(size_t)(dir * 24 + i) * 1024 + row] = v;
    }
    uint4* wt4 = (uint4*)wtail;
#pragma unroll
    for (int ku = 0; ku < 8; ++ku) {
        const float* s8 = src + 192 + ku * 8;
        uint4 v;
        v.x = packh2(s8[0], s8[1]);
        v.y = packh2(s8[2], s8[3]);
        v.z = packh2(s8[4], s8[5]);
        v.w = packh2(s8[6], s8[7]);
        wt4[(size_t)(dir * 8 + ku) * 1024 + row] = v;
    }
}

// ---------------- BiLSTM recurrent: 8 blocks (dir x batch), 512 threads ------------------
// Thread t owns rows t (i/f for t<256/t>=256... precisely: rows t and t+512; t<256 ->
// (i,g) of cell t, t>=256 -> (f,o) of cell t-256). Weights cols 0..191 in 2x96 VGPRs,
// cols 192..255 in LDS as per-row uint4 (16 conflict-free b128 reads/step). All h
// broadcasts as b128. amdgpu_waves_per_eu(2,2): pins budget at 256 VGPR (R3/R5 lesson:
// launch_bounds arg2 is only an occupancy hint -> allocator capped 128 and spilled).
__global__ void __attribute__((amdgpu_flat_work_group_size(512, 512), amdgpu_waves_per_eu(2, 2)))
lstm_kernel(const float* __restrict__ xp,
            const uint32_t* __restrict__ wreg,
            const uint32_t* __restrict__ wtail,
            float* __restrict__ hT) {
    int blk = blockIdx.x;
    int dir = blk >> 2, batch = blk & 3;
    int t = threadIdx.x;                      // rows t, t+512
    uint32_t wa[96], wb[96];
    {
        const uint4* ra = (const uint4*)wreg + (size_t)dir * 24 * 1024;
#pragma unroll
        for (int i = 0; i < 24; ++i) {
            uint4 v = ra[i * 1024 + t];
            wa[i * 4 + 0] = v.x; wa[i * 4 + 1] = v.y; wa[i * 4 + 2] = v.z; wa[i * 4 + 3] = v.w;
        }
#pragma unroll
        for (int i = 0; i < 24; ++i) {
            uint4 v = ra[i * 1024 + 512 + t];
            wb[i * 4 + 0] = v.x; wb[i * 4 + 1] = v.y; wb[i * 4 + 2] = v.z; wb[i * 4 + 3] = v.w;
        }
    }
    __shared__ __align__(16) uint4 wlds[8 * 1024];   // 128 KB tail, [ku][row]
    __shared__ __align__(16) uint32_t h_pk[128];     // h as 128 half2 pairs
    __shared__ __align__(8) float2 fo_lds[256];
    {
        const uint4* tsrc = (const uint4*)wtail + (size_t)dir * 8 * 1024;
        for (int i = t; i < 8 * 1024; i += 512) wlds[i] = tsrc[i];
    }
    if (t < 128) h_pk[t] = 0;
    __syncthreads();
    float creg = 0.f;
    const float* xpb = xp + dir * 131072 + batch * 1024;
#pragma unroll 1
    for (int step = 0; step < 32; ++step) {
        int teff = dir ? (31 - step) : step;
        float xa = xpb[teff * 4096 + t];
        float xb = xpb[teff * 4096 + 512 + t];
        float acca = 0.f, accb = 0.f;
#pragma unroll
        for (int q = 0; q < 24; ++q) {
            uint4 hq = *(const uint4*)&h_pk[q * 4];   // same-address broadcast b128
            acca = dot2(wa[q * 4 + 0], hq.x, acca);
            acca = dot2(wa[q * 4 + 1], hq.y, acca);
            acca = dot2(wa[q * 4 + 2], hq.z, acca);
            acca = dot2(wa[q * 4 + 3], hq.w, acca);
            accb = dot2(wb[q * 4 + 0], hq.x, accb);
            accb = dot2(wb[q * 4 + 1], hq.y, accb);
            accb = dot2(wb[q * 4 + 2], hq.z, accb);
            accb = dot2(wb[q * 4 + 3], hq.w, accb);
        }
#pragma unroll
        for (int ku = 0; ku < 8; ++ku) {
            uint4 hq = *(const uint4*)&h_pk[96 + ku * 4];  // broadcast b128
            uint4 qa = wlds[ku * 1024 + t];                // conflict-free b128
            uint4 qb = wlds[ku * 1024 + 512 + t];
            acca = dot2(qa.x, hq.x, acca); acca = dot2(qa.y, hq.y, acca);
            acca = dot2(qa.z, hq.z, acca); acca = dot2(qa.w, hq.w, acca);
            accb = dot2(qb.x, hq.x, accb); accb = dot2(qb.y, hq.y, accb);
            accb = dot2(qb.z, hq.z, accb); accb = dot2(qb.w, hq.w, accb);
        }
        float ga = acca + xa;                 // t<256: i-gate; t>=256: f-gate
        float gb = accb + xb;                 // t<256: g-gate; t>=256: o-gate
        if (t >= 256) fo_lds[t - 256] = make_float2(ga, gb);
        __syncthreads();
        if (t < 256) {
            float2 fo = fo_lds[t];
            creg = sigf(fo.x) * creg + sigf(ga) * tanhfast(gb);
            float hv = sigf(fo.y) * tanhfast(creg);
            if (step == 31) hT[(size_t)(dir * 4 + batch) * 256 + t] = hv;
            float hnext = __shfl_down(hv, 1, 64);
            if ((t & 1) == 0) h_pk[t >> 1] = packh2(hv, hnext);
        }
        __syncthreads();
    }
}

// ---------------- heads: mu/logvar/pi from concat(h_f, h_b) ----------------
__global__ __launch_bounds__(256) void heads_kernel(const float* __restrict__ hT,
                                                    const float* __restrict__ Wmu, const float* __restrict__ bmu,
                                                    const float* __restrict__ Wlv, const float* __restrict__ blv,
                                                    const float* __restrict__ Wpi, const float* __restrict__ bpi,
                                                    float* __restrict__ out) {
    __shared__ __align__(16) float feat[4][512];
    int tid = threadIdx.x;
    for (int i = tid; i < 2048; i += 256) {
        int b = i >> 9, j = i & 511;
        int d = j >> 8, jj = j & 255;
        feat[b][j] = hT[(size_t)(d * 4 + b) * 256 + jj];
    }
    __syncthreads();
    int o = blockIdx.x * 256 + tid;
    if (o >= 4128) return;
    const float* Wr;
    float bv;
    int kind, m;
    if (o < 2048) { Wr = Wmu + (size_t)o * 512; bv = bmu[o]; kind = 0; m = o; }
    else if (o < 4096) { m = o - 2048; Wr = Wlv + (size_t)m * 512; bv = blv[m]; kind = 1; }
    else { m = o - 4096; Wr = Wpi + (size_t)m * 512; bv = bpi[m]; kind = 2; }
    float s0 = bv, s1 = bv, s2 = bv, s3 = bv;
    for (int k = 0; k < 512; k += 4) {
        float4 wv = *(const float4*)(Wr + k);
        s0 += feat[0][k] * wv.x + feat[0][k + 1] * wv.y + feat[0][k + 2] * wv.z + feat[0][k + 3] * wv.w;
        s1 += feat[1][k] * wv.x + feat[1][k + 1] * wv.y + feat[1][k + 2] * wv.z + feat[1][k + 3] * wv.w;
        s2 += feat[2][k] * wv.x + feat[2][k + 1] * wv.y + feat[2][k + 2] * wv.z + feat[2][k + 3] * wv.w;
        s3 += feat[3][k] * wv.x + feat[3][k + 1] * wv.y + feat[3][k + 2] * wv.z + feat[3][k + 3] * wv.w;
    }
    if (kind == 0) {
        out[0 * 2048 + m] = s0; out[1 * 2048 + m] = s1; out[2 * 2048 + m] = s2; out[3 * 2048 + m] = s3;
    } else if (kind == 1) {
        out[8192 + 0 * 2048 + m] = s0; out[8192 + 1 * 2048 + m] = s1;
        out[8192 + 2 * 2048 + m] = s2; out[8192 + 3 * 2048 + m] = s3;
    } else {
        out[16384 + 0 * 32 + m] = s0; out[16384 + 1 * 32 + m] = s1;
        out[16384 + 2 * 32 + m] = s2; out[16384 + 3 * 32 + m] = s3;
    }
}

extern "C" void kernel_launch(void* const* d_in, const int* in_sizes, int n_in,
                              void* d_out, int out_size, void* d_ws, size_t ws_size,
                              hipStream_t stream) {
    const float* x = (const float*)d_in[0];
    const int* ei = (const int*)d_in[1];
    const float* W1 = (const float*)d_in[2];
    const float* as1 = (const float*)d_in[3];
    const float* ad1 = (const float*)d_in[4];
    const float* b1 = (const float*)d_in[5];
    const float* W2 = (const float*)d_in[6];
    const float* as2 = (const float*)d_in[7];
    const float* ad2 = (const float*)d_in[8];
    const float* b2 = (const float*)d_in[9];
    const float* W3 = (const float*)d_in[10];
    const float* as3 = (const float*)d_in[11];
    const float* ad3 = (const float*)d_in[12];
    const float* b3 = (const float*)d_in[13];
    const float* Wih_f = (const float*)d_in[14];
    const float* Whh_f = (const float*)d_in[15];
    const float* bih_f = (const float*)d_in[16];
    const float* bhh_f = (const float*)d_in[17];
    const float* Wih_b = (const float*)d_in[18];
    const float* Whh_b = (const float*)d_in[19];
    const float* bih_b = (const float*)d_in[20];
    const float* bhh_b = (const float*)d_in[21];
    const float* Wmu = (const float*)d_in[22];
    const float* bmu = (const float*)d_in[23];
    const float* Wlv = (const float*)d_in[24];
    const float* blv = (const float*)d_in[25];
    const float* Wpi = (const float*)d_in[26];
    const float* bpi = (const float*)d_in[27];

    float* ws = (float*)d_ws;
    float* bufA = ws;                    // 4,194,304 f32 (feature buffer)
    float* bufB = ws + 4194304;          // 4,194,304 f32 (output buffer)
    float* asb = ws + 8388608;           // 65,536
    float* adb = ws + 8454144;           // 65,536
    int* cnt = (int*)(ws + 8519680);     // 128 ints
    int* col = cnt + 128;                // 32,768 ints
    float* xp = ws + 8560768;            // 262,144
    float* hT = ws + 8822912;            // 2,048 (final h per dir x batch)
    uint32_t* wreg = (uint32_t*)ws;      // 196,608 u32 — overlaps bufA (dead by then)
    uint32_t* wtail = wreg + 196608;     // 65,536 u32
    float* out = (float*)d_out;

    build_csr_kernel<<<1, 1024, 0, stream>>>(ei, cnt, col);

    // GAT layer 1
    gemm128_kernel<<<dim3(2, 128), 256, 0, stream>>>(x, W1, bufA, NNODE, 256, 64);
    att_kernel<4><<<4096, 256, 0, stream>>>(bufA, as1, ad1, asb, adb);
    agg_kernel<4><<<4096, 256, 0, stream>>>(bufA, asb, adb, cnt, col, b1, bufB);
    // GAT layer 2
    gemm128_kernel<<<dim3(2, 128), 256, 0, stream>>>(bufB, W2, bufA, NNODE, 256, 256);
    att_kernel<4><<<4096, 256, 0, stream>>>(bufA, as2, ad2, asb, adb);
    agg_kernel<4><<<4096, 256, 0, stream>>>(bufA, asb, adb, cnt, col, b2, bufB);
    // GAT layer 3 (single head, N=64)
    gemm_kernel<<<dim3(1, 256), 256, 0, stream>>>(bufB, W3, bufA, NNODE, 64, 256);
    att_kernel<1><<<4096, 256, 0, stream>>>(bufA, as3, ad3, asb, adb);
    agg_kernel<1><<<4096, 256, 0, stream>>>(bufA, asb, adb, cnt, col, b3, bufB);
    // bufA dead from here on -> wreg/wtail may overwrite its first 1 MB
    wpack_kernel<<<8, 256, 0, stream>>>(Whh_f, Whh_b, wreg, wtail);
    // fused pool+xpart, BiLSTM, heads
    poolx_kernel<<<128, 256, 0, stream>>>(bufB, Wih_f, bih_f, bhh_f, Wih_b, bih_b, bhh_b, xp);
    lstm_kernel<<<8, 512, 0, stream>>>(xp, wreg, wtail, hT);
    heads_kernel<<<17, 256, 0, stream>>>(hT, Wmu, bmu, Wlv, blv, Wpi, bpi, out);
}

// Round 7
// 307.706 us; speedup vs baseline: 1.6800x; 1.2805x over previous
//
#include <hip/hip_runtime.h>
#include <hip/hip_bf16.h>
#include <cstdint>

#define NLOC 128        // nodes per graph
#define NGRAPH 128      // bs*T
#define NNODE 16384     // total nodes
#define EBASE 2048      // base edges per graph
#define CSTRIDE 256     // csr col stride per local node

typedef _Float16 half2v __attribute__((ext_vector_type(2)));

__device__ __forceinline__ float sigf(float x) { return 1.f / (1.f + __expf(-x)); }
__device__ __forceinline__ float tanhfast(float x) {
    float e = __expf(2.f * x);
    return 1.f - 2.f / (e + 1.f);
}
__device__ __forceinline__ uint32_t packh2(float a, float b) {
    half2v v;
    v.x = (_Float16)a; v.y = (_Float16)b;
    return __builtin_bit_cast(uint32_t, v);
}
__device__ __forceinline__ float dot2(uint32_t w, uint32_t h, float acc) {
#if __has_builtin(__builtin_amdgcn_fdot2)
    return __builtin_amdgcn_fdot2(__builtin_bit_cast(half2v, w),
                                  __builtin_bit_cast(half2v, h), acc, false);
#else
    half2v wv = __builtin_bit_cast(half2v, w);
    half2v hv = __builtin_bit_cast(half2v, h);
    return acc + (float)wv.x * (float)hv.x + (float)wv.y * (float)hv.y;
#endif
}

// ---------------- CSR of the shared per-graph edge list (dst -> list of src) --------------
// One block per destination node v (128 blocks x 256 threads). Thread j scans edges
// [8j, 8j+8); stable edge-order preserved via LDS prefix of per-thread match counts.
// (R6 lesson: the old 1-block serial version was 95 us at 0.17% occupancy.)
__global__ __launch_bounds__(256) void build_csr_kernel(const int* __restrict__ ei,
                                                        int* __restrict__ cnt,
                                                        int* __restrict__ col) {
    __shared__ int m_l[256];
    int v = blockIdx.x, j = threadIdx.x;
    const int* srcs = ei;
    const int* dsts = ei + EBASE;
    int e0 = j * 8;
    int d[8];
#pragma unroll
    for (int k = 0; k < 8; ++k) d[k] = dsts[e0 + k];
    int mycnt = 0;
#pragma unroll
    for (int k = 0; k < 8; ++k) mycnt += (d[k] == v);
    m_l[j] = mycnt;
    __syncthreads();
    int start = 0;
    for (int q = 0; q < 256; ++q) {
        int mv = m_l[q];                 // broadcast read, uniform loop
        if (q < j) start += mv;
    }
    if (j == 255) cnt[v] = start + mycnt;
    int w = v * CSTRIDE + start;
#pragma unroll
    for (int k = 0; k < 8; ++k) {
        if (d[k] == v) col[w++] = srcs[e0 + k];
    }
}

// ---------------- fp32 GEMM 128x128 tile, 8x8 micro-tile: C[M,N]=A@B; M%128==0,N%128==0,K%16==0
__global__ __launch_bounds__(256) void gemm128_kernel(const float* __restrict__ A,
                                                      const float* __restrict__ B,
                                                      float* __restrict__ C,
                                                      int M, int N, int K) {
    __shared__ __align__(16) float As[16][128];   // [k][m]
    __shared__ __align__(16) float Bs[16][128];   // [k][n]
    int tid = threadIdx.x;
    int bm = blockIdx.y, bn = blockIdx.x;
    int ar = tid >> 1, ak = (tid & 1) * 8;        // A: row ar, k-offset ak
    int bk = tid >> 4, bc = (tid & 15) * 8;       // B: k-row bk, col bc
    int ty = tid >> 4, tx = tid & 15;             // output 8x8 at (ty*8, tx*8)
    const float* Ab = A + (size_t)(bm * 128 + ar) * K;
    const float* Bb = B + (size_t)bn * 128 + bc;
    float acc[8][8] = {};
    for (int k0 = 0; k0 < K; k0 += 16) {
        float4 a0 = *(const float4*)(Ab + k0 + ak);
        float4 a1 = *(const float4*)(Ab + k0 + ak + 4);
        float4 b0 = *(const float4*)(Bb + (size_t)(k0 + bk) * N);
        float4 b1 = *(const float4*)(Bb + (size_t)(k0 + bk) * N + 4);
        As[ak + 0][ar] = a0.x; As[ak + 1][ar] = a0.y; As[ak + 2][ar] = a0.z; As[ak + 3][ar] = a0.w;
        As[ak + 4][ar] = a1.x; As[ak + 5][ar] = a1.y; As[ak + 6][ar] = a1.z; As[ak + 7][ar] = a1.w;
        *(float4*)&Bs[bk][bc] = b0;
        *(float4*)&Bs[bk][bc + 4] = b1;
        __syncthreads();
#pragma unroll
        for (int kk = 0; kk < 16; ++kk) {
            float4 x0 = *(const float4*)&As[kk][ty * 8];
            float4 x1 = *(const float4*)&As[kk][ty * 8 + 4];
            float4 y0 = *(const float4*)&Bs[kk][tx * 8];
            float4 y1 = *(const float4*)&Bs[kk][tx * 8 + 4];
            float xa[8] = {x0.x, x0.y, x0.z, x0.w, x1.x, x1.y, x1.z, x1.w};
            float yb[8] = {y0.x, y0.y, y0.z, y0.w, y1.x, y1.y, y1.z, y1.w};
#pragma unroll
            for (int i = 0; i < 8; ++i)
#pragma unroll
                for (int j = 0; j < 8; ++j) acc[i][j] += xa[i] * yb[j];
        }
        __syncthreads();
    }
    float* Cb = C + (size_t)(bm * 128 + ty * 8) * N + (size_t)bn * 128 + tx * 8;
#pragma unroll
    for (int i = 0; i < 8; ++i) {
        *(float4*)(Cb + (size_t)i * N) = make_float4(acc[i][0], acc[i][1], acc[i][2], acc[i][3]);
        *(float4*)(Cb + (size_t)i * N + 4) = make_float4(acc[i][4], acc[i][5], acc[i][6], acc[i][7]);
    }
}

// ---------------- fp32 tiled GEMM 64x64 (kept for N=64 layer-3) ----------------
__global__ __launch_bounds__(256) void gemm_kernel(const float* __restrict__ A,
                                                   const float* __restrict__ B,
                                                   float* __restrict__ C,
                                                   int M, int N, int K) {
    __shared__ __align__(16) float As[16][64];
    __shared__ __align__(16) float Bs[16][64];
    int tid = threadIdx.x;
    int bm = blockIdx.y, bn = blockIdx.x;
    int am = tid >> 2, ak = (tid & 3) << 2;
    int bk = tid >> 4, bn4 = (tid & 15) << 2;
    int ty = tid >> 4, tx = tid & 15;
    const float* Ab = A + (size_t)bm * 64 * K;
    const float* Bb = B + bn * 64;
    float acc[4][4] = {};
    for (int k0 = 0; k0 < K; k0 += 16) {
        float4 av = *(const float4*)(Ab + (size_t)am * K + k0 + ak);
        float4 bv = *(const float4*)(Bb + (size_t)(k0 + bk) * N + bn4);
        As[ak + 0][am] = av.x; As[ak + 1][am] = av.y;
        As[ak + 2][am] = av.z; As[ak + 3][am] = av.w;
        *(float4*)&Bs[bk][bn4] = bv;
        __syncthreads();
#pragma unroll
        for (int kk = 0; kk < 16; ++kk) {
            float4 a4 = *(const float4*)&As[kk][ty << 2];
            float4 b4 = *(const float4*)&Bs[kk][tx << 2];
            acc[0][0] += a4.x * b4.x; acc[0][1] += a4.x * b4.y; acc[0][2] += a4.x * b4.z; acc[0][3] += a4.x * b4.w;
            acc[1][0] += a4.y * b4.x; acc[1][1] += a4.y * b4.y; acc[1][2] += a4.y * b4.z; acc[1][3] += a4.y * b4.w;
            acc[2][0] += a4.z * b4.x; acc[2][1] += a4.z * b4.y; acc[2][2] += a4.z * b4.z; acc[2][3] += a4.z * b4.w;
            acc[3][0] += a4.w * b4.x; acc[3][1] += a4.w * b4.y; acc[3][2] += a4.w * b4.z; acc[3][3] += a4.w * b4.w;
        }
        __syncthreads();
    }
    float* Cb = C + (size_t)(bm * 64 + ty * 4) * N + bn * 64 + tx * 4;
#pragma unroll
    for (int i = 0; i < 4; ++i)
        *(float4*)(Cb + (size_t)i * N) = make_float4(acc[i][0], acc[i][1], acc[i][2], acc[i][3]);
}

// ---------------- attention dot products per node ----------------
template <int H>
__global__ __launch_bounds__(256) void att_kernel(const float* __restrict__ hf,
                                                  const float* __restrict__ a_s,
                                                  const float* __restrict__ a_d,
                                                  float* __restrict__ asb,
                                                  float* __restrict__ adb) {
    int lane = threadIdx.x & 63;
    int n = blockIdx.x * 4 + (threadIdx.x >> 6);
    const float* row = hf + (size_t)n * (H * 64);
#pragma unroll
    for (int h = 0; h < H; ++h) {
        float v = row[h * 64 + lane];
        float ps = v * a_s[h * 64 + lane];
        float pd = v * a_d[h * 64 + lane];
#pragma unroll
        for (int off = 32; off > 0; off >>= 1) {
            ps += __shfl_xor(ps, off, 64);
            pd += __shfl_xor(pd, off, 64);
        }
        if (lane == 0) { asb[n * H + h] = ps; adb[n * H + h] = pd; }
    }
}

// ---------------- GAT aggregation: softmax over in-edges, gather, +bias, ReLU -------------
template <int H>
__global__ __launch_bounds__(256) void agg_kernel(const float* __restrict__ hf,
                                                  const float* __restrict__ asb,
                                                  const float* __restrict__ adb,
                                                  const int* __restrict__ cnt,
                                                  const int* __restrict__ col,
                                                  const float* __restrict__ bias,
                                                  float* __restrict__ out) {
    __shared__ float e_lds[4][96][H];
    __shared__ int u_lds[4][96];
    int lane = threadIdx.x & 63, w = threadIdx.x >> 6;
    int n = blockIdx.x * 4 + w;
    int v = n & 127, base = n & ~127;
    int deg = cnt[v];
    int tot = min(deg + 1, 96);
    float adst[H];
#pragma unroll
    for (int h = 0; h < H; ++h) adst[h] = adb[n * H + h];
    for (int k = lane; k < tot; k += 64) {
        int u = (k < deg) ? col[v * CSTRIDE + k] : v;
        u_lds[w][k] = u;
#pragma unroll
        for (int h = 0; h < H; ++h) {
            float e = asb[(base + u) * H + h] + adst[h];
            e_lds[w][k][h] = (e > 0.f) ? e : 0.2f * e;
        }
    }
    __syncthreads();
    float m[H];
#pragma unroll
    for (int h = 0; h < H; ++h) m[h] = -1e30f;
    for (int k = 0; k < tot; ++k)
#pragma unroll
        for (int h = 0; h < H; ++h) m[h] = fmaxf(m[h], e_lds[w][k][h]);
    __syncthreads();
    for (int k = lane; k < tot; k += 64)
#pragma unroll
        for (int h = 0; h < H; ++h) e_lds[w][k][h] = __expf(e_lds[w][k][h] - m[h]);
    __syncthreads();
    float den[H], acc[H];
#pragma unroll
    for (int h = 0; h < H; ++h) { den[h] = 0.f; acc[h] = 0.f; }
    for (int k = 0; k < tot; ++k) {
        int u = u_lds[w][k];
        const float* hr = hf + (size_t)(base + u) * (H * 64);
#pragma unroll
        for (int h = 0; h < H; ++h) {
            float wgt = e_lds[w][k][h];
            den[h] += wgt;
            acc[h] += wgt * hr[h * 64 + lane];
        }
    }
#pragma unroll
    for (int h = 0; h < H; ++h) {
        float o = acc[h] / (den[h] + 1e-16f) + bias[h * 64 + lane];
        out[(size_t)n * (H * 64) + h * 64 + lane] = fmaxf(o, 0.f);
    }
}

// ---------------- fused pool + LSTM input part --------------------------------------------
__global__ __launch_bounds__(256) void poolx_kernel(const float* __restrict__ h,
                                                    const float* __restrict__ Wf, const float* __restrict__ bif, const float* __restrict__ bhf,
                                                    const float* __restrict__ Wb, const float* __restrict__ bib, const float* __restrict__ bhb,
                                                    float* __restrict__ xp) {
    __shared__ float part_l[4][64];
    __shared__ float emb[64];
    int g = blockIdx.x, tid = threadIdx.x;
    int c = tid & 63, prt = tid >> 6;
    {
        const float* p = h + (size_t)g * 8192 + prt * 32 * 64 + c;
        float s = 0.f;
#pragma unroll
        for (int vv = 0; vv < 32; ++vv) s += p[vv * 64];
        part_l[prt][c] = s;
    }
    __syncthreads();
    if (tid < 64) emb[tid] = part_l[0][tid] + part_l[1][tid] + part_l[2][tid] + part_l[3][tid];
    __syncthreads();
    int r = (g & 31) * 4 + (g >> 5);
    for (int dir = 0; dir < 2; ++dir) {
        const float* W = dir ? Wb : Wf;
        const float* bi = dir ? bib : bif;
        const float* bh = dir ? bhb : bhf;
        for (int o = tid; o < 1024; o += 256) {
            const float* wr = W + (size_t)o * 64;
            float s = bi[o] + bh[o];
#pragma unroll
            for (int k = 0; k < 64; k += 4) {
                float4 wv = *(const float4*)(wr + k);
                s += emb[k] * wv.x + emb[k + 1] * wv.y + emb[k + 2] * wv.z + emb[k + 3] * wv.w;
            }
            xp[dir * 131072 + r * 1024 + o] = s;
        }
    }
}

// ---------------- pre-pack Whh to f16 pairs: reg part [dir][i][row] uint4 (cols 0..191),
//                  tail part [dir][ku][row] uint4 (cols 192+8ku..199+8ku) ----------------
__global__ __launch_bounds__(256) void wpack_kernel(const float* __restrict__ Whh_f,
                                                    const float* __restrict__ Whh_b,
                                                    uint32_t* __restrict__ wreg,
                                                    uint32_t* __restrict__ wtail) {
    int gid = blockIdx.x * 256 + threadIdx.x;   // 0..2047
    int dir = gid >> 10, row = gid & 1023;
    const float* src = (dir ? Whh_b : Whh_f) + (size_t)row * 256;
    uint4* wr4 = (uint4*)wreg;
#pragma unroll
    for (int i = 0; i < 24; ++i) {
        uint4 v;
        v.x = packh2(src[i * 8 + 0], src[i * 8 + 1]);
        v.y = packh2(src[i * 8 + 2], src[i * 8 + 3]);
        v.z = packh2(src[i * 8 + 4], src[i * 8 + 5]);
        v.w = packh2(src[i * 8 + 6], src[i * 8 + 7]);
        wr4[(size_t)(dir * 24 + i) * 1024 + row] = v;
    }
    uint4* wt4 = (uint4*)wtail;
#pragma unroll
    for (int ku = 0; ku < 8; ++ku) {
        const float* s8 = src + 192 + ku * 8;
        uint4 v;
        v.x = packh2(s8[0], s8[1]);
        v.y = packh2(s8[2], s8[3]);
        v.z = packh2(s8[4], s8[5]);
        v.w = packh2(s8[6], s8[7]);
        wt4[(size_t)(dir * 8 + ku) * 1024 + row] = v;
    }
}

// ---------------- BiLSTM recurrent: 8 blocks (dir x batch), 512 threads ------------------
__global__ void __attribute__((amdgpu_flat_work_group_size(512, 512), amdgpu_waves_per_eu(2, 2)))
lstm_kernel(const float* __restrict__ xp,
            const uint32_t* __restrict__ wreg,
            const uint32_t* __restrict__ wtail,
            float* __restrict__ hT) {
    int blk = blockIdx.x;
    int dir = blk >> 2, batch = blk & 3;
    int t = threadIdx.x;                      // rows t, t+512
    uint32_t wa[96], wb[96];
    {
        const uint4* ra = (const uint4*)wreg + (size_t)dir * 24 * 1024;
#pragma unroll
        for (int i = 0; i < 24; ++i) {
            uint4 v = ra[i * 1024 + t];
            wa[i * 4 + 0] = v.x; wa[i * 4 + 1] = v.y; wa[i * 4 + 2] = v.z; wa[i * 4 + 3] = v.w;
        }
#pragma unroll
        for (int i = 0; i < 24; ++i) {
            uint4 v = ra[i * 1024 + 512 + t];
            wb[i * 4 + 0] = v.x; wb[i * 4 + 1] = v.y; wb[i * 4 + 2] = v.z; wb[i * 4 + 3] = v.w;
        }
    }
    __shared__ __align__(16) uint4 wlds[8 * 1024];   // 128 KB tail, [ku][row]
    __shared__ __align__(16) uint32_t h_pk[128];     // h as 128 half2 pairs
    __shared__ __align__(8) float2 fo_lds[256];
    {
        const uint4* tsrc = (const uint4*)wtail + (size_t)dir * 8 * 1024;
        for (int i = t; i < 8 * 1024; i += 512) wlds[i] = tsrc[i];
    }
    if (t < 128) h_pk[t] = 0;
    __syncthreads();
    float creg = 0.f;
    const float* xpb = xp + dir * 131072 + batch * 1024;
#pragma unroll 1
    for (int step = 0; step < 32; ++step) {
        int teff = dir ? (31 - step) : step;
        float xa = xpb[teff * 4096 + t];
        float xb = xpb[teff * 4096 + 512 + t];
        float acca = 0.f, accb = 0.f;
#pragma unroll
        for (int q = 0; q < 24; ++q) {
            uint4 hq = *(const uint4*)&h_pk[q * 4];   // same-address broadcast b128
            acca = dot2(wa[q * 4 + 0], hq.x, acca);
            acca = dot2(wa[q * 4 + 1], hq.y, acca);
            acca = dot2(wa[q * 4 + 2], hq.z, acca);
            acca = dot2(wa[q * 4 + 3], hq.w, acca);
            accb = dot2(wb[q * 4 + 0], hq.x, accb);
            accb = dot2(wb[q * 4 + 1], hq.y, accb);
            accb = dot2(wb[q * 4 + 2], hq.z, accb);
            accb = dot2(wb[q * 4 + 3], hq.w, accb);
        }
#pragma unroll
        for (int ku = 0; ku < 8; ++ku) {
            uint4 hq = *(const uint4*)&h_pk[96 + ku * 4];  // broadcast b128
            uint4 qa = wlds[ku * 1024 + t];                // conflict-free b128
            uint4 qb = wlds[ku * 1024 + 512 + t];
            acca = dot2(qa.x, hq.x, acca); acca = dot2(qa.y, hq.y, acca);
            acca = dot2(qa.z, hq.z, acca); acca = dot2(qa.w, hq.w, acca);
            accb = dot2(qb.x, hq.x, accb); accb = dot2(qb.y, hq.y, accb);
            accb = dot2(qb.z, hq.z, accb); accb = dot2(qb.w, hq.w, accb);
        }
        float ga = acca + xa;                 // t<256: i-gate; t>=256: f-gate
        float gb = accb + xb;                 // t<256: g-gate; t>=256: o-gate
        if (t >= 256) fo_lds[t - 256] = make_float2(ga, gb);
        __syncthreads();
        if (t < 256) {
            float2 fo = fo_lds[t];
            creg = sigf(fo.x) * creg + sigf(ga) * tanhfast(gb);
            float hv = sigf(fo.y) * tanhfast(creg);
            if (step == 31) hT[(size_t)(dir * 4 + batch) * 256 + t] = hv;
            float hnext = __shfl_down(hv, 1, 64);
            if ((t & 1) == 0) h_pk[t >> 1] = packh2(hv, hnext);
        }
        __syncthreads();
    }
}

// ---------------- heads: mu/logvar/pi from concat(h_f, h_b) ----------------
__global__ __launch_bounds__(256) void heads_kernel(const float* __restrict__ hT,
                                                    const float* __restrict__ Wmu, const float* __restrict__ bmu,
                                                    const float* __restrict__ Wlv, const float* __restrict__ blv,
                                                    const float* __restrict__ Wpi, const float* __restrict__ bpi,
                                                    float* __restrict__ out) {
    __shared__ __align__(16) float feat[4][512];
    int tid = threadIdx.x;
    for (int i = tid; i < 2048; i += 256) {
        int b = i >> 9, j = i & 511;
        int d = j >> 8, jj = j & 255;
        feat[b][j] = hT[(size_t)(d * 4 + b) * 256 + jj];
    }
    __syncthreads();
    int o = blockIdx.x * 256 + tid;
    if (o >= 4128) return;
    const float* Wr;
    float bv;
    int kind, m;
    if (o < 2048) { Wr = Wmu + (size_t)o * 512; bv = bmu[o]; kind = 0; m = o; }
    else if (o < 4096) { m = o - 2048; Wr = Wlv + (size_t)m * 512; bv = blv[m]; kind = 1; }
    else { m = o - 4096; Wr = Wpi + (size_t)m * 512; bv = bpi[m]; kind = 2; }
    float s0 = bv, s1 = bv, s2 = bv, s3 = bv;
    for (int k = 0; k < 512; k += 4) {
        float4 wv = *(const float4*)(Wr + k);
        s0 += feat[0][k] * wv.x + feat[0][k + 1] * wv.y + feat[0][k + 2] * wv.z + feat[0][k + 3] * wv.w;
        s1 += feat[1][k] * wv.x + feat[1][k + 1] * wv.y + feat[1][k + 2] * wv.z + feat[1][k + 3] * wv.w;
        s2 += feat[2][k] * wv.x + feat[2][k + 1] * wv.y + feat[2][k + 2] * wv.z + feat[2][k + 3] * wv.w;
        s3 += feat[3][k] * wv.x + feat[3][k + 1] * wv.y + feat[3][k + 2] * wv.z + feat[3][k + 3] * wv.w;
    }
    if (kind == 0) {
        out[0 * 2048 + m] = s0; out[1 * 2048 + m] = s1; out[2 * 2048 + m] = s2; out[3 * 2048 + m] = s3;
    } else if (kind == 1) {
        out[8192 + 0 * 2048 + m] = s0; out[8192 + 1 * 2048 + m] = s1;
        out[8192 + 2 * 2048 + m] = s2; out[8192 + 3 * 2048 + m] = s3;
    } else {
        out[16384 + 0 * 32 + m] = s0; out[16384 + 1 * 32 + m] = s1;
        out[16384 + 2 * 32 + m] = s2; out[16384 + 3 * 32 + m] = s3;
    }
}

extern "C" void kernel_launch(void* const* d_in, const int* in_sizes, int n_in,
                              void* d_out, int out_size, void* d_ws, size_t ws_size,
                              hipStream_t stream) {
    const float* x = (const float*)d_in[0];
    const int* ei = (const int*)d_in[1];
    const float* W1 = (const float*)d_in[2];
    const float* as1 = (const float*)d_in[3];
    const float* ad1 = (const float*)d_in[4];
    const float* b1 = (const float*)d_in[5];
    const float* W2 = (const float*)d_in[6];
    const float* as2 = (const float*)d_in[7];
    const float* ad2 = (const float*)d_in[8];
    const float* b2 = (const float*)d_in[9];
    const float* W3 = (const float*)d_in[10];
    const float* as3 = (const float*)d_in[11];
    const float* ad3 = (const float*)d_in[12];
    const float* b3 = (const float*)d_in[13];
    const float* Wih_f = (const float*)d_in[14];
    const float* Whh_f = (const float*)d_in[15];
    const float* bih_f = (const float*)d_in[16];
    const float* bhh_f = (const float*)d_in[17];
    const float* Wih_b = (const float*)d_in[18];
    const float* Whh_b = (const float*)d_in[19];
    const float* bih_b = (const float*)d_in[20];
    const float* bhh_b = (const float*)d_in[21];
    const float* Wmu = (const float*)d_in[22];
    const float* bmu = (const float*)d_in[23];
    const float* Wlv = (const float*)d_in[24];
    const float* blv = (const float*)d_in[25];
    const float* Wpi = (const float*)d_in[26];
    const float* bpi = (const float*)d_in[27];

    float* ws = (float*)d_ws;
    float* bufA = ws;                    // 4,194,304 f32 (feature buffer)
    float* bufB = ws + 4194304;          // 4,194,304 f32 (output buffer)
    float* asb = ws + 8388608;           // 65,536
    float* adb = ws + 8454144;           // 65,536
    int* cnt = (int*)(ws + 8519680);     // 128 ints
    int* col = cnt + 128;                // 32,768 ints
    float* xp = ws + 8560768;            // 262,144
    float* hT = ws + 8822912;            // 2,048 (final h per dir x batch)
    uint32_t* wreg = (uint32_t*)ws;      // 196,608 u32 — overlaps bufA (dead by then)
    uint32_t* wtail = wreg + 196608;     // 65,536 u32
    float* out = (float*)d_out;

    build_csr_kernel<<<128, 256, 0, stream>>>(ei, cnt, col);

    // GAT layer 1
    gemm128_kernel<<<dim3(2, 128), 256, 0, stream>>>(x, W1, bufA, NNODE, 256, 64);
    att_kernel<4><<<4096, 256, 0, stream>>>(bufA, as1, ad1, asb, adb);
    agg_kernel<4><<<4096, 256, 0, stream>>>(bufA, asb, adb, cnt, col, b1, bufB);
    // GAT layer 2
    gemm128_kernel<<<dim3(2, 128), 256, 0, stream>>>(bufB, W2, bufA, NNODE, 256, 256);
    att_kernel<4><<<4096, 256, 0, stream>>>(bufA, as2, ad2, asb, adb);
    agg_kernel<4><<<4096, 256, 0, stream>>>(bufA, asb, adb, cnt, col, b2, bufB);
    // GAT layer 3 (single head, N=64)
    gemm_kernel<<<dim3(1, 256), 256, 0, stream>>>(bufB, W3, bufA, NNODE, 64, 256);
    att_kernel<1><<<4096, 256, 0, stream>>>(bufA, as3, ad3, asb, adb);
    agg_kernel<1><<<4096, 256, 0, stream>>>(bufA, asb, adb, cnt, col, b3, bufB);
    // bufA dead from here on -> wreg/wtail may overwrite its first 1 MB
    wpack_kernel<<<8, 256, 0, stream>>>(Whh_f, Whh_b, wreg, wtail);
    // fused pool+xpart, BiLSTM, heads
    poolx_kernel<<<128, 256, 0, stream>>>(bufB, Wih_f, bih_f, bhh_f, Wih_b, bih_b, bhh_b, xp);
    lstm_kernel<<<8, 512, 0, stream>>>(xp, wreg, wtail, hT);
    heads_kernel<<<17, 256, 0, stream>>>(hT, Wmu, bmu, Wlv, blv, Wpi, bpi, out);
}